// Round 3
// baseline (7512.367 us; speedup 1.0000x reference)
//
#include <hip/hip_runtime.h>
#include <hip/hip_bf16.h>
#include <math.h>

#define BB 32
#define LL 2048
#define INP 192
#define OUTC 2
#define HH 512
#define NN2 32
#define NNL 4

__device__ __forceinline__ float gelu_erf(float x) {
  return 0.5f * x * (1.0f + erff(x * 0.70710678118654752f));
}

__device__ __forceinline__ float sigmoidf_(float x) {
  return 1.0f / (1.0f + expf(-x));
}

// ---------------------------------------------------------------------------
// Precompute per-(layer,h,n) discretized params: w = exp(dt*A), Ct2 = 2*C*(w-1)/A
// P layout: [NL][H][N2][4] = {w_re, w_im, c2_re, c2_im}
// ---------------------------------------------------------------------------
__global__ __launch_bounds__(256) void k_params(const float* __restrict__ log_dt,
                                                const float* __restrict__ Cri,
                                                const float* __restrict__ lAr,
                                                const float* __restrict__ Aim,
                                                float* __restrict__ P) {
  int idx = blockIdx.x * 256 + threadIdx.x;   // (i*H + h)*N2 + n
  if (idx >= NNL * HH * NN2) return;
  float dt  = expf(log_dt[idx / NN2]);
  float Are = -expf(lAr[idx]);
  float Aimv = Aim[idx];
  float dre = Are * dt, dim = Aimv * dt;
  float er = expf(dre);
  float wrv = er * cosf(dim);
  float wiv = er * sinf(dim);
  float Er = wrv - 1.0f, Ei = wiv;
  float den = Are * Are + Aimv * Aimv;
  float Fr = (Er * Are + Ei * Aimv) / den;
  float Fi = (Ei * Are - Er * Aimv) / den;
  float Cre = Cri[idx * 2 + 0], Cim = Cri[idx * 2 + 1];
  P[idx * 4 + 0] = wrv;
  P[idx * 4 + 1] = wiv;
  P[idx * 4 + 2] = 2.0f * (Cre * Fr - Cim * Fi);
  P[idx * 4 + 3] = 2.0f * (Cre * Fi + Cim * Fr);
}

// ---------------------------------------------------------------------------
// Input GEMM: U[b,h,l] = sum_k X[b,l,k] * W[k,h] + bias[h]
// Tile 128h x 128l, K-chunks of 32, 256 threads, 8x8 micro-tiles (split 2x2).
// b here is LOCAL batch index within the current group (grid.z).
// ---------------------------------------------------------------------------
__global__ __launch_bounds__(256) void k_ingemm(const float* __restrict__ X,
                                                const float* __restrict__ W,
                                                const float* __restrict__ bias,
                                                float* __restrict__ U) {
  __shared__ float At[32][132];  // At[k][h_local]
  __shared__ float Bt[32][132];  // Bt[k][l_local]
  int lt = blockIdx.x * 128;
  int ht = blockIdx.y * 128;
  int b  = blockIdx.z;
  int tid = threadIdx.x;
  int tr = tid >> 4, tc = tid & 15;
  int r0 = tr * 4, c0 = tc * 4;
  float acc[2][2][4][4] = {};
  for (int kt = 0; kt < INP; kt += 32) {
    for (int i = tid; i < 32 * 128; i += 256) {
      int k = i >> 7, r = i & 127;
      At[k][r] = W[(size_t)(kt + k) * HH + ht + r];
    }
    {
      int k4 = (tid & 7) * 4;
      int cb = tid >> 3;
      #pragma unroll
      for (int p = 0; p < 4; ++p) {
        int c = cb + 32 * p;
        const float4 v = *reinterpret_cast<const float4*>(
            &X[((size_t)b * LL + lt + c) * INP + kt + k4]);
        Bt[k4 + 0][c] = v.x; Bt[k4 + 1][c] = v.y;
        Bt[k4 + 2][c] = v.z; Bt[k4 + 3][c] = v.w;
      }
    }
    __syncthreads();
    #pragma unroll
    for (int k = 0; k < 32; ++k) {
      float4 a0 = *reinterpret_cast<const float4*>(&At[k][r0]);
      float4 a1 = *reinterpret_cast<const float4*>(&At[k][r0 + 64]);
      float4 b0 = *reinterpret_cast<const float4*>(&Bt[k][c0]);
      float4 b1 = *reinterpret_cast<const float4*>(&Bt[k][c0 + 64]);
      float ar[2][4] = {{a0.x, a0.y, a0.z, a0.w}, {a1.x, a1.y, a1.z, a1.w}};
      float bc[2][4] = {{b0.x, b0.y, b0.z, b0.w}, {b1.x, b1.y, b1.z, b1.w}};
      #pragma unroll
      for (int p = 0; p < 2; ++p)
        #pragma unroll
        for (int q = 0; q < 2; ++q)
          #pragma unroll
          for (int i = 0; i < 4; ++i)
            #pragma unroll
            for (int j = 0; j < 4; ++j)
              acc[p][q][i][j] = fmaf(ar[p][i], bc[q][j], acc[p][q][i][j]);
    }
    __syncthreads();
  }
  #pragma unroll
  for (int p = 0; p < 2; ++p)
    #pragma unroll
    for (int i = 0; i < 4; ++i) {
      int h = ht + r0 + p * 64 + i;
      float bv = bias[h];
      #pragma unroll
      for (int q = 0; q < 2; ++q) {
        float4 o;
        o.x = acc[p][q][i][0] + bv;
        o.y = acc[p][q][i][1] + bv;
        o.z = acc[p][q][i][2] + bv;
        o.w = acc[p][q][i][3] + bv;
        *reinterpret_cast<float4*>(&U[((size_t)b * HH + h) * LL + lt + c0 + q * 64]) = o;
      }
    }
}

// ---------------------------------------------------------------------------
// S4D scan: per (local-b,h) row, 4 lanes x 8 complex modes each.
// s_n[l] = w_n * s_n[l-1] + u[l];  yconv[l] = sum_n Re(c2_n * s_n[l])
// Y[l] = gelu(yconv + D*u).  Quad shuffle-reduce.
// ---------------------------------------------------------------------------
__global__ __launch_bounds__(256) void k_scan(const float* __restrict__ U,
                                              float* __restrict__ Y,
                                              const float* __restrict__ P,
                                              const float* __restrict__ Dp) {
  int tid = threadIdx.x;
  int g = tid >> 2, lid = tid & 3;
  int row = blockIdx.x * 64 + g;       // row = b_local*H + h
  int h = row & (HH - 1);
  float wr[8], wi[8], cr[8], ci[8], sr[8], si[8];
  const float* p = P + ((size_t)h * NN2 + lid * 8) * 4;
  #pragma unroll
  for (int m = 0; m < 8; ++m) {
    wr[m] = p[m * 4 + 0]; wi[m] = p[m * 4 + 1];
    cr[m] = p[m * 4 + 2]; ci[m] = p[m * 4 + 3];
    sr[m] = 0.0f; si[m] = 0.0f;
  }
  float Dv = Dp[h];
  const float* urow = U + (size_t)row * LL;
  float* yrow = Y + (size_t)row * LL;
  for (int l0 = 0; l0 < LL; l0 += 16) {
    float y4[4] = {0.f, 0.f, 0.f, 0.f};
    #pragma unroll
    for (int jj = 0; jj < 4; ++jj) {
      float4 uf = *reinterpret_cast<const float4*>(&urow[l0 + jj * 4]);
      float uv[4] = {uf.x, uf.y, uf.z, uf.w};
      #pragma unroll
      for (int j = 0; j < 4; ++j) {
        float u = uv[j];
        float partial = 0.0f;
        #pragma unroll
        for (int m = 0; m < 8; ++m) {
          float nr = fmaf(wr[m], sr[m], u);
          nr = fmaf(-wi[m], si[m], nr);
          float ni = fmaf(wi[m], sr[m], wr[m] * si[m]);
          sr[m] = nr; si[m] = ni;
          partial = fmaf(cr[m], nr, partial);
          partial = fmaf(-ci[m], ni, partial);
        }
        partial += __shfl_xor(partial, 1);
        partial += __shfl_xor(partial, 2);
        if (lid == jj) {
          float v = partial + Dv * u;
          y4[j] = gelu_erf(v);
        }
      }
    }
    *reinterpret_cast<float4*>(&yrow[l0 + lid * 4]) =
        make_float4(y4[0], y4[1], y4[2], y4[3]);
  }
}

// ---------------------------------------------------------------------------
// conv1x1 + GLU fused: per local batch b,
//   z[o,l]   = sum_h CW[o,h]   * Y[h,l] + CB[o]      (o in [0,2H))
//   U[o,l]   = z[o,l] * sigmoid(z[o+H,l])            (o in [0,H))
// Tile: 64 output channels (=> 128 dot rows: a-half + gate-half) x 128 l.
// ---------------------------------------------------------------------------
__global__ __launch_bounds__(256) void k_conv(const float* __restrict__ Y,
                                              const float* __restrict__ CW,
                                              const float* __restrict__ CB,
                                              float* __restrict__ U) {
  __shared__ float Wt[32][132];  // Wt[k][r]: r<64 a-rows, r>=64 gate-rows
  __shared__ float Yt[32][132];  // Yt[k][c]
  int lt = blockIdx.x * 128;
  int ot = blockIdx.y * 64;
  int b  = blockIdx.z;
  int tid = threadIdx.x;
  int tr = tid >> 4, tc = tid & 15;
  int r0 = tr * 4, c0 = tc * 4;
  float acc[2][2][4][4] = {};
  for (int kt = 0; kt < HH; kt += 32) {
    {
      int k4 = (tid & 7) * 4;
      int rb = tid >> 3;
      #pragma unroll
      for (int p = 0; p < 4; ++p) {
        int r = rb + 32 * p;
        int orow = (r < 64) ? (ot + r) : (HH + ot + (r - 64));
        const float4 v = *reinterpret_cast<const float4*>(
            &CW[(size_t)orow * HH + kt + k4]);
        Wt[k4 + 0][r] = v.x; Wt[k4 + 1][r] = v.y;
        Wt[k4 + 2][r] = v.z; Wt[k4 + 3][r] = v.w;
      }
      int c4 = (tid & 31) * 4;
      int kb = tid >> 5;
      #pragma unroll
      for (int p = 0; p < 4; ++p) {
        int k = kb + 8 * p;
        *reinterpret_cast<float4*>(&Yt[k][c4]) =
            *reinterpret_cast<const float4*>(
                &Y[((size_t)b * HH + kt + k) * LL + lt + c4]);
      }
    }
    __syncthreads();
    #pragma unroll
    for (int k = 0; k < 32; ++k) {
      float4 a0 = *reinterpret_cast<const float4*>(&Wt[k][r0]);        // a-rows
      float4 a1 = *reinterpret_cast<const float4*>(&Wt[k][r0 + 64]);   // gate-rows
      float4 b0 = *reinterpret_cast<const float4*>(&Yt[k][c0]);
      float4 b1 = *reinterpret_cast<const float4*>(&Yt[k][c0 + 64]);
      float ar[2][4] = {{a0.x, a0.y, a0.z, a0.w}, {a1.x, a1.y, a1.z, a1.w}};
      float bc[2][4] = {{b0.x, b0.y, b0.z, b0.w}, {b1.x, b1.y, b1.z, b1.w}};
      #pragma unroll
      for (int p = 0; p < 2; ++p)
        #pragma unroll
        for (int q = 0; q < 2; ++q)
          #pragma unroll
          for (int i = 0; i < 4; ++i)
            #pragma unroll
            for (int j = 0; j < 4; ++j)
              acc[p][q][i][j] = fmaf(ar[p][i], bc[q][j], acc[p][q][i][j]);
    }
    __syncthreads();
  }
  float cba[4], cbb[4];
  #pragma unroll
  for (int i = 0; i < 4; ++i) {
    cba[i] = CB[ot + r0 + i];
    cbb[i] = CB[HH + ot + r0 + i];
  }
  #pragma unroll
  for (int i = 0; i < 4; ++i) {
    #pragma unroll
    for (int q = 0; q < 2; ++q) {
      float4 o;
      float a0 = acc[0][q][i][0] + cba[i], g0 = acc[1][q][i][0] + cbb[i];
      float a1 = acc[0][q][i][1] + cba[i], g1 = acc[1][q][i][1] + cbb[i];
      float a2 = acc[0][q][i][2] + cba[i], g2 = acc[1][q][i][2] + cbb[i];
      float a3 = acc[0][q][i][3] + cba[i], g3 = acc[1][q][i][3] + cbb[i];
      o.x = a0 * sigmoidf_(g0);
      o.y = a1 * sigmoidf_(g1);
      o.z = a2 * sigmoidf_(g2);
      o.w = a3 * sigmoidf_(g3);
      *reinterpret_cast<float4*>(
          &U[((size_t)b * HH + ot + r0 + i) * LL + lt + c0 + q * 64]) = o;
    }
  }
}

// ---------------------------------------------------------------------------
// Output projection: out[b,l,o] = sum_h U[b,h,l] * Wo[h,o] + bo[o].
// FP32 OUTPUT (reference returns float32). b is local; `out` pre-offset.
// ---------------------------------------------------------------------------
__global__ __launch_bounds__(256) void k_outgemm(const float* __restrict__ U,
                                                 const float* __restrict__ Wo,
                                                 const float* __restrict__ bo,
                                                 float* __restrict__ out) {
  int bl = blockIdx.x * 256 + threadIdx.x;   // [0, G*L)
  int b = bl >> 11, l = bl & (LL - 1);
  float a0 = 0.0f, a1 = 0.0f;
  const float* up = U + (size_t)b * HH * LL + l;
  #pragma unroll 4
  for (int h = 0; h < HH; ++h) {
    float v = up[(size_t)h * LL];
    a0 = fmaf(v, Wo[h * 2 + 0], a0);
    a1 = fmaf(v, Wo[h * 2 + 1], a1);
  }
  a0 += bo[0];
  a1 += bo[1];
  out[(size_t)bl * 2 + 0] = a0;
  out[(size_t)bl * 2 + 1] = a1;
}

extern "C" void kernel_launch(void* const* d_in, const int* in_sizes, int n_in,
                              void* d_out, int out_size, void* d_ws, size_t ws_size,
                              hipStream_t stream) {
  const float* X      = (const float*)d_in[0];
  const float* Win    = (const float*)d_in[1];
  const float* bin    = (const float*)d_in[2];
  const float* log_dt = (const float*)d_in[3];
  const float* Cri    = (const float*)d_in[4];
  const float* lAr    = (const float*)d_in[5];
  const float* Aim    = (const float*)d_in[6];
  const float* Dp     = (const float*)d_in[7];
  const float* CW     = (const float*)d_in[8];
  const float* CB     = (const float*)d_in[9];
  const float* Wo     = (const float*)d_in[10];
  const float* bo     = (const float*)d_in[11];
  float* out = (float*)d_out;   // reference output dtype is float32

  // Workspace layout: [P: NL*H*N2*4 floats][U: G*H*L floats][Y: G*H*L floats]
  const size_t Pfloats = (size_t)NNL * HH * NN2 * 4;   // 262144 floats (1 MiB)
  const size_t per_b   = (size_t)HH * LL;              // 1 Mi floats (4 MiB) per batch
  float* P = (float*)d_ws;

  size_t ws_floats = ws_size / sizeof(float);
  size_t avail = (ws_floats > Pfloats) ? (ws_floats - Pfloats) : 0;
  int G = (int)(avail / (2 * per_b));
  if (G > BB) G = BB;
  if (G < 1) G = 1;

  float* U = P + Pfloats;
  float* Y = U + (size_t)G * per_b;

  k_params<<<(NNL * HH * NN2 + 255) / 256, 256, 0, stream>>>(log_dt, Cri, lAr, Aim, P);

  for (int b0 = 0; b0 < BB; b0 += G) {
    int g = (BB - b0 < G) ? (BB - b0) : G;
    k_ingemm<<<dim3(LL / 128, HH / 128, g), 256, 0, stream>>>(
        X + (size_t)b0 * LL * INP, Win, bin, U);
    for (int layer = 0; layer < NNL; ++layer) {
      k_scan<<<g * HH / 64, 256, 0, stream>>>(
          U, Y, P + (size_t)layer * HH * NN2 * 4, Dp + (size_t)layer * HH);
      k_conv<<<dim3(LL / 128, HH / 64, g), 256, 0, stream>>>(
          Y, CW + (size_t)layer * 2 * HH * HH, CB + (size_t)layer * 2 * HH, U);
    }
    k_outgemm<<<g * LL / 256, 256, 0, stream>>>(
        U, Wo, bo, out + (size_t)b0 * LL * OUTC);
  }
}

// Round 4
// 2485.676 us; speedup vs baseline: 3.0223x; 3.0223x over previous
//
#include <hip/hip_runtime.h>
#include <hip/hip_bf16.h>
#include <math.h>

#define BB 32
#define LL 2048
#define INP 192
#define OUTC 2
#define HH 512
#define NN2 32
#define NNL 4

using short8 = __attribute__((ext_vector_type(8))) short;
using f32x4  = __attribute__((ext_vector_type(4))) float;

__device__ __forceinline__ float gelu_erf(float x) {
  return 0.5f * x * (1.0f + erff(x * 0.70710678118654752f));
}

__device__ __forceinline__ float sigmoidf_(float x) {
  return 1.0f / (1.0f + expf(-x));
}

__device__ __forceinline__ void gload16(const void* gsrc, void* ldst) {
  __builtin_amdgcn_global_load_lds(
      (const __attribute__((address_space(1))) void*)gsrc,
      (__attribute__((address_space(3))) void*)ldst, 16, 0, 0);
}

// ---------------------------------------------------------------------------
// Param precompute: P[NL][H][N2][4] = {w_re, w_im, c2_re, c2_im}
// ---------------------------------------------------------------------------
__global__ __launch_bounds__(256) void k_params(const float* __restrict__ log_dt,
                                                const float* __restrict__ Cri,
                                                const float* __restrict__ lAr,
                                                const float* __restrict__ Aim,
                                                float* __restrict__ P) {
  int idx = blockIdx.x * 256 + threadIdx.x;
  if (idx >= NNL * HH * NN2) return;
  float dt  = expf(log_dt[idx / NN2]);
  float Are = -expf(lAr[idx]);
  float Aimv = Aim[idx];
  float dre = Are * dt, dim = Aimv * dt;
  float er = expf(dre);
  float wrv = er * cosf(dim);
  float wiv = er * sinf(dim);
  float Er = wrv - 1.0f, Ei = wiv;
  float den = Are * Are + Aimv * Aimv;
  float Fr = (Er * Are + Ei * Aimv) / den;
  float Fi = (Ei * Are - Er * Aimv) / den;
  float Cre = Cri[idx * 2 + 0], Cim = Cri[idx * 2 + 1];
  P[idx * 4 + 0] = wrv;
  P[idx * 4 + 1] = wiv;
  P[idx * 4 + 2] = 2.0f * (Cre * Fr - Cim * Fi);
  P[idx * 4 + 3] = 2.0f * (Cre * Fi + Cim * Fr);
}

// ---------------------------------------------------------------------------
// fp32 -> bf16 weight convert (CW, all layers), 4 elems/thread.
// ---------------------------------------------------------------------------
__global__ __launch_bounds__(256) void k_tobf16(const float* __restrict__ src,
                                                __hip_bfloat16* __restrict__ dst,
                                                int n) {
  int i = (blockIdx.x * 256 + threadIdx.x) * 4;
  if (i >= n) return;
  float4 v = *reinterpret_cast<const float4*>(&src[i]);
  dst[i + 0] = __float2bfloat16(v.x);
  dst[i + 1] = __float2bfloat16(v.y);
  dst[i + 2] = __float2bfloat16(v.z);
  dst[i + 3] = __float2bfloat16(v.w);
}

// ---------------------------------------------------------------------------
// Input GEMM (fp32): U[b,h,l] = sum_k X[b,l,k] * W[k,h] + bias[h]
// ---------------------------------------------------------------------------
__global__ __launch_bounds__(256) void k_ingemm(const float* __restrict__ X,
                                                const float* __restrict__ W,
                                                const float* __restrict__ bias,
                                                float* __restrict__ U) {
  __shared__ float At[32][132];
  __shared__ float Bt[32][132];
  int lt = blockIdx.x * 128;
  int ht = blockIdx.y * 128;
  int b  = blockIdx.z;
  int tid = threadIdx.x;
  int tr = tid >> 4, tc = tid & 15;
  int r0 = tr * 4, c0 = tc * 4;
  float acc[2][2][4][4] = {};
  for (int kt = 0; kt < INP; kt += 32) {
    for (int i = tid; i < 32 * 128; i += 256) {
      int k = i >> 7, r = i & 127;
      At[k][r] = W[(size_t)(kt + k) * HH + ht + r];
    }
    {
      int k4 = (tid & 7) * 4;
      int cb = tid >> 3;
      #pragma unroll
      for (int p = 0; p < 4; ++p) {
        int c = cb + 32 * p;
        const float4 v = *reinterpret_cast<const float4*>(
            &X[((size_t)b * LL + lt + c) * INP + kt + k4]);
        Bt[k4 + 0][c] = v.x; Bt[k4 + 1][c] = v.y;
        Bt[k4 + 2][c] = v.z; Bt[k4 + 3][c] = v.w;
      }
    }
    __syncthreads();
    #pragma unroll
    for (int k = 0; k < 32; ++k) {
      float4 a0 = *reinterpret_cast<const float4*>(&At[k][r0]);
      float4 a1 = *reinterpret_cast<const float4*>(&At[k][r0 + 64]);
      float4 b0 = *reinterpret_cast<const float4*>(&Bt[k][c0]);
      float4 b1 = *reinterpret_cast<const float4*>(&Bt[k][c0 + 64]);
      float ar[2][4] = {{a0.x, a0.y, a0.z, a0.w}, {a1.x, a1.y, a1.z, a1.w}};
      float bc[2][4] = {{b0.x, b0.y, b0.z, b0.w}, {b1.x, b1.y, b1.z, b1.w}};
      #pragma unroll
      for (int p = 0; p < 2; ++p)
        #pragma unroll
        for (int q = 0; q < 2; ++q)
          #pragma unroll
          for (int i = 0; i < 4; ++i)
            #pragma unroll
            for (int j = 0; j < 4; ++j)
              acc[p][q][i][j] = fmaf(ar[p][i], bc[q][j], acc[p][q][i][j]);
    }
    __syncthreads();
  }
  #pragma unroll
  for (int p = 0; p < 2; ++p)
    #pragma unroll
    for (int i = 0; i < 4; ++i) {
      int h = ht + r0 + p * 64 + i;
      float bv = bias[h];
      #pragma unroll
      for (int q = 0; q < 2; ++q) {
        float4 o;
        o.x = acc[p][q][i][0] + bv;
        o.y = acc[p][q][i][1] + bv;
        o.z = acc[p][q][i][2] + bv;
        o.w = acc[p][q][i][3] + bv;
        *reinterpret_cast<float4*>(&U[((size_t)b * HH + h) * LL + lt + c0 + q * 64]) = o;
      }
    }
}

// ---------------------------------------------------------------------------
// S4D scan: 16 lanes per (b,h) row, 2 complex modes per lane.
// Block = 256 thr = 16 rows (16 consecutive h of one local batch).
// Grid = g * (H/16).  4096 waves at g=32 -> 4 waves/SIMD.
// Output: Yt[b][l][h] bf16 (transposed via LDS) = gelu(yconv + D*u).
// ---------------------------------------------------------------------------
__global__ __launch_bounds__(256) void k_scan(const float* __restrict__ U,
                                              __hip_bfloat16* __restrict__ Yt,
                                              const float* __restrict__ P,
                                              const float* __restrict__ Dp) {
  __shared__ __hip_bfloat16 yl[32][16];   // [l_local][h_local]
  int t = threadIdx.x;
  int grp = t >> 4;          // h_local 0..15
  int k16 = t & 15;          // lane in group
  int blk = blockIdx.x;
  int b  = blk >> 5;         // H/16 = 32 blocks per batch
  int h0 = (blk & 31) * 16;
  int h = h0 + grp;
  int row = b * HH + h;
  const float4* pp = reinterpret_cast<const float4*>(P + ((size_t)h * NN2 + 2 * k16) * 4);
  float4 p0 = pp[0], p1 = pp[1];
  float wr0 = p0.x, wi0 = p0.y, cr0 = p0.z, ci0 = p0.w;
  float wr1 = p1.x, wi1 = p1.y, cr1 = p1.z, ci1 = p1.w;
  float sr0 = 0.f, si0 = 0.f, sr1 = 0.f, si1 = 0.f;
  float Dv = Dp[h];
  const float* urow = U + (size_t)row * LL;
  for (int l0 = 0; l0 < LL; l0 += 32) {
    float ua = urow[l0 + k16];
    float ub = urow[l0 + 16 + k16];
    float keep0 = 0.f, keep1 = 0.f;
    #pragma unroll
    for (int j = 0; j < 32; ++j) {
      float u = __shfl((j < 16) ? ua : ub, j & 15, 16);
      float nr0 = fmaf(wr0, sr0, u);  nr0 = fmaf(-wi0, si0, nr0);
      float ni0 = fmaf(wi0, sr0, wr0 * si0);
      sr0 = nr0; si0 = ni0;
      float nr1 = fmaf(wr1, sr1, u);  nr1 = fmaf(-wi1, si1, nr1);
      float ni1 = fmaf(wi1, sr1, wr1 * si1);
      sr1 = nr1; si1 = ni1;
      float p = fmaf(cr0, nr0, fmaf(-ci0, ni0, fmaf(cr1, nr1, -ci1 * ni1)));
      p += __shfl_xor(p, 1, 16);
      p += __shfl_xor(p, 2, 16);
      p += __shfl_xor(p, 4, 16);
      p += __shfl_xor(p, 8, 16);
      if ((j & 15) == k16) {
        float val = p + Dv * u;
        if (j < 16) keep0 = val; else keep1 = val;
      }
    }
    yl[k16][grp]      = __float2bfloat16(gelu_erf(keep0));
    yl[16 + k16][grp] = __float2bfloat16(gelu_erf(keep1));
    __syncthreads();
    if (t < 128) {
      int lr = t >> 2, ch = t & 3;    // 32 l-rows x 4 chunks of 8B
      float2 v = *reinterpret_cast<const float2*>(&yl[lr][ch * 4]);
      *reinterpret_cast<float2*>(
          &Yt[((size_t)b * LL + l0 + lr) * HH + h0 + ch * 4]) = v;
    }
    __syncthreads();
  }
}

// ---------------------------------------------------------------------------
// conv1x1 + GLU, bf16 MFMA (16x16x32), fp32 accumulate.
//   z[o,l] = sum_h CWb[o,h] * Yt[l,h];  U[o,l] = (za+cba)*sigmoid(zg+cbg)
// Block: 128 M-rows (64 a-rows + 64 gate-rows) x 128 l, BK=64.
// LDS: A[128][64] bf16 + B[128][64] bf16 (B stored as Yt rows = [l][h]).
// T2 swizzle: byte col ^= ((row&7)<<4); staged via pre-swizzled global src.
// 4 waves in 2x2; each wave owns 32 a-rows + their 32 gate-rows -> in-reg GLU.
// ---------------------------------------------------------------------------
__global__ __launch_bounds__(256) void k_conv(const __hip_bfloat16* __restrict__ Ytb,
                                              const __hip_bfloat16* __restrict__ CWb,
                                              const float* __restrict__ CB,
                                              float* __restrict__ U) {
  __shared__ short Alds[128 * 64];
  __shared__ short Blds[128 * 64];
  int lt = blockIdx.x * 128;
  int ot = blockIdx.y * 64;
  int b  = blockIdx.z;
  int t = threadIdx.x;
  int wid = t >> 6, lane = t & 63;
  int wr = wid >> 1, wc = wid & 1;
  int l15 = lane & 15, l4 = lane >> 4;
  f32x4 zero = {0.f, 0.f, 0.f, 0.f};
  f32x4 accA[2][4], accG[2][4];
  #pragma unroll
  for (int m = 0; m < 2; ++m)
    #pragma unroll
    for (int n = 0; n < 4; ++n) { accA[m][n] = zero; accG[m][n] = zero; }

  const char* Yb = (const char*)(Ytb + (size_t)b * LL * HH);
  const char* Wb = (const char*)CWb;

  for (int kt = 0; kt < HH; kt += 64) {
    // stage A (CW rows): 16KB, 4 x 16B per thread
    #pragma unroll
    for (int it = 0; it < 4; ++it) {
      int d = 16 * (t + 256 * it);
      int rowl = d >> 7, cb = d & 127;
      int orow = (rowl < 64) ? (ot + rowl) : (448 + ot + rowl);  // 512+ot+(rowl-64)
      gload16(Wb + (size_t)orow * 1024 + kt * 2 + (cb ^ ((rowl & 7) << 4)),
              (char*)Alds + d);
    }
    // stage B (Yt rows): 16KB
    #pragma unroll
    for (int it = 0; it < 4; ++it) {
      int d = 16 * (t + 256 * it);
      int rowl = d >> 7, cb = d & 127;
      gload16(Yb + ((size_t)(lt + rowl) * 512 + kt) * 2 + (cb ^ ((rowl & 7) << 4)),
              (char*)Blds + d);
    }
    __syncthreads();
    #pragma unroll
    for (int ks = 0; ks < 2; ++ks) {
      short8 af[4], bf[4];
      #pragma unroll
      for (int m = 0; m < 4; ++m) {
        int mrow = ((m < 2) ? (wr * 32 + m * 16) : (64 + wr * 32 + (m - 2) * 16)) + l15;
        int colb = (ks * 64 + 16 * l4) ^ ((mrow & 7) << 4);
        af[m] = *reinterpret_cast<const short8*>((const char*)Alds + mrow * 128 + colb);
      }
      #pragma unroll
      for (int n = 0; n < 4; ++n) {
        int nrow = wc * 64 + n * 16 + l15;
        int colb = (ks * 64 + 16 * l4) ^ ((nrow & 7) << 4);
        bf[n] = *reinterpret_cast<const short8*>((const char*)Blds + nrow * 128 + colb);
      }
      #pragma unroll
      for (int m = 0; m < 2; ++m)
        #pragma unroll
        for (int n = 0; n < 4; ++n) {
          accA[m][n] = __builtin_amdgcn_mfma_f32_16x16x32_bf16(af[m], bf[n], accA[m][n], 0, 0, 0);
          accG[m][n] = __builtin_amdgcn_mfma_f32_16x16x32_bf16(af[m + 2], bf[n], accG[m][n], 0, 0, 0);
        }
    }
    __syncthreads();
  }
  // epilogue: GLU in-register, store U[o][l] fp32
  #pragma unroll
  for (int m = 0; m < 2; ++m) {
    #pragma unroll
    for (int r = 0; r < 4; ++r) {
      int rowl = wr * 32 + m * 16 + l4 * 4 + r;   // local a-row 0..63
      float ba = CB[ot + rowl];
      float bg = CB[512 + ot + rowl];
      float* urow_ = U + ((size_t)b * HH + ot + rowl) * LL + lt + wc * 64;
      #pragma unroll
      for (int n = 0; n < 4; ++n) {
        float a = accA[m][n][r] + ba;
        float g = accG[m][n][r] + bg;
        urow_[n * 16 + l15] = a * sigmoidf_(g);
      }
    }
  }
}

// ---------------------------------------------------------------------------
// Output projection (fp32 out).
// ---------------------------------------------------------------------------
__global__ __launch_bounds__(256) void k_outgemm(const float* __restrict__ U,
                                                 const float* __restrict__ Wo,
                                                 const float* __restrict__ bo,
                                                 float* __restrict__ out) {
  int bl = blockIdx.x * 256 + threadIdx.x;
  int b = bl >> 11, l = bl & (LL - 1);
  float a0 = 0.0f, a1 = 0.0f;
  const float* up = U + (size_t)b * HH * LL + l;
  #pragma unroll 4
  for (int h = 0; h < HH; ++h) {
    float v = up[(size_t)h * LL];
    a0 = fmaf(v, Wo[h * 2 + 0], a0);
    a1 = fmaf(v, Wo[h * 2 + 1], a1);
  }
  out[(size_t)bl * 2 + 0] = a0 + bo[0];
  out[(size_t)bl * 2 + 1] = a1 + bo[1];
}

extern "C" void kernel_launch(void* const* d_in, const int* in_sizes, int n_in,
                              void* d_out, int out_size, void* d_ws, size_t ws_size,
                              hipStream_t stream) {
  const float* X      = (const float*)d_in[0];
  const float* Win    = (const float*)d_in[1];
  const float* bin    = (const float*)d_in[2];
  const float* log_dt = (const float*)d_in[3];
  const float* Cri    = (const float*)d_in[4];
  const float* lAr    = (const float*)d_in[5];
  const float* Aim    = (const float*)d_in[6];
  const float* Dp     = (const float*)d_in[7];
  const float* CW     = (const float*)d_in[8];
  const float* CB     = (const float*)d_in[9];
  const float* Wo     = (const float*)d_in[10];
  const float* bo     = (const float*)d_in[11];
  float* out = (float*)d_out;

  // ws layout: [P 262144 f][CWb 2M bf16 = 1M f][U: G*H*L f][Yt: G*L*H bf16 = G*HL/2 f]
  const size_t Pfloats  = (size_t)NNL * HH * NN2 * 4;          // 262144
  const size_t CWfloats = (size_t)NNL * 2 * HH * HH / 2;       // 1048576
  const size_t HL       = (size_t)HH * LL;                     // 1048576
  float* P = (float*)d_ws;
  __hip_bfloat16* CWb = (__hip_bfloat16*)(P + Pfloats);

  size_t ws_floats = ws_size / sizeof(float);
  size_t head = Pfloats + CWfloats;
  size_t avail = (ws_floats > head) ? (ws_floats - head) : 0;
  int G = (int)(avail / (HL + HL / 2));
  if (G > BB) G = BB;
  if (G < 1) G = 1;

  float* U = P + head;
  __hip_bfloat16* Yt = (__hip_bfloat16*)(U + (size_t)G * HL);

  k_params<<<(NNL * HH * NN2 + 255) / 256, 256, 0, stream>>>(log_dt, Cri, lAr, Aim, P);
  k_tobf16<<<(NNL * 2 * HH * HH) / 1024, 256, 0, stream>>>(CW, CWb, NNL * 2 * HH * HH);

  for (int b0 = 0; b0 < BB; b0 += G) {
    int g = (BB - b0 < G) ? (BB - b0) : G;
    k_ingemm<<<dim3(LL / 128, HH / 128, g), 256, 0, stream>>>(
        X + (size_t)b0 * LL * INP, Win, bin, U);
    for (int layer = 0; layer < NNL; ++layer) {
      k_scan<<<g * (HH / 16), 256, 0, stream>>>(
          U, Yt, P + (size_t)layer * HH * NN2 * 4, Dp + (size_t)layer * HH);
      k_conv<<<dim3(LL / 128, HH / 64, g), 256, 0, stream>>>(
          Yt, CWb + (size_t)layer * 2 * HH * HH, CB + (size_t)layer * 2 * HH, U);
    }
    k_outgemm<<<g * LL / 256, 256, 0, stream>>>(
        U, Wo, bo, out + (size_t)b0 * LL * OUTC);
  }
}

// Round 5
// 1932.886 us; speedup vs baseline: 3.8866x; 1.2860x over previous
//
#include <hip/hip_runtime.h>
#include <hip/hip_bf16.h>
#include <math.h>

#define BB 32
#define LL 2048
#define INP 192
#define OUTC 2
#define HH 512
#define NN2 32
#define NNL 4

using short8 = __attribute__((ext_vector_type(8))) short;
using f32x4  = __attribute__((ext_vector_type(4))) float;

__device__ __forceinline__ float gelu_erf(float x) {
  return 0.5f * x * (1.0f + erff(x * 0.70710678118654752f));
}
__device__ __forceinline__ float sigmoidf_(float x) {
  return 1.0f / (1.0f + expf(-x));
}
__device__ __forceinline__ unsigned short bf16bits(float x) {
  __hip_bfloat16 b = __float2bfloat16(x);
  return __builtin_bit_cast(unsigned short, b);
}
__device__ __forceinline__ void gload16(const void* gsrc, void* ldst) {
  __builtin_amdgcn_global_load_lds(
      (const __attribute__((address_space(1))) void*)gsrc,
      (__attribute__((address_space(3))) void*)ldst, 16, 0, 0);
}

// ---------------------------------------------------------------------------
// P[NL][H][N2][4] = {w_re, w_im, c2_re, c2_im}
// ---------------------------------------------------------------------------
__global__ __launch_bounds__(256) void k_params(const float* __restrict__ log_dt,
                                                const float* __restrict__ Cri,
                                                const float* __restrict__ lAr,
                                                const float* __restrict__ Aim,
                                                float* __restrict__ P) {
  int idx = blockIdx.x * 256 + threadIdx.x;
  if (idx >= NNL * HH * NN2) return;
  float dt  = expf(log_dt[idx / NN2]);
  float Are = -expf(lAr[idx]);
  float Aimv = Aim[idx];
  float dre = Are * dt, dim = Aimv * dt;
  float er = expf(dre);
  float wrv = er * cosf(dim);
  float wiv = er * sinf(dim);
  float Er = wrv - 1.0f, Ei = wiv;
  float den = Are * Are + Aimv * Aimv;
  float Fr = (Er * Are + Ei * Aimv) / den;
  float Fi = (Ei * Are - Er * Aimv) / den;
  float Cre = Cri[idx * 2 + 0], Cim = Cri[idx * 2 + 1];
  P[idx * 4 + 0] = wrv;
  P[idx * 4 + 1] = wiv;
  P[idx * 4 + 2] = 2.0f * (Cre * Fr - Cim * Fi);
  P[idx * 4 + 3] = 2.0f * (Cre * Fi + Cim * Fr);
}

// ---------------------------------------------------------------------------
// Tables for chunked scan: V[(layer,h,n)][d=0..15] = w^d (complex interleaved)
// Kt[(layer,h)][d=0..15] = Re sum_n c2_n w_n^d.
// Block 256 = 8 h-instances x 32 lanes (lane = mode n).
// ---------------------------------------------------------------------------
__global__ __launch_bounds__(256) void k_tables(const float* __restrict__ P,
                                                float* __restrict__ V,
                                                float* __restrict__ Kt) {
  int t = threadIdx.x;
  int n = t & 31;
  int inst = blockIdx.x * 8 + (t >> 5);     // (layer*H + h)
  size_t idx = (size_t)inst * NN2 + n;
  float4 pq = reinterpret_cast<const float4*>(P)[idx];
  float wr = pq.x, wi = pq.y, c2r = pq.z, c2i = pq.w;
  float pr = 1.0f, pi = 0.0f;
  float* vrow = V + idx * 32;
  for (int d = 0; d < 16; ++d) {
    vrow[2 * d] = pr; vrow[2 * d + 1] = pi;
    float kp = c2r * pr - c2i * pi;
    #pragma unroll
    for (int k = 1; k < 32; k <<= 1) kp += __shfl_xor(kp, k, 32);
    if (n == 0) Kt[(size_t)inst * 16 + d] = kp;
    float nr = pr * wr - pi * wi;
    pi = pr * wi + pi * wr;
    pr = nr;
  }
}

// ---------------------------------------------------------------------------
// fp32 -> bf16 convert (CW weights).
// ---------------------------------------------------------------------------
__global__ __launch_bounds__(256) void k_tobf16(const float* __restrict__ src,
                                                __hip_bfloat16* __restrict__ dst,
                                                int n) {
  int i = (blockIdx.x * 256 + threadIdx.x) * 4;
  if (i >= n) return;
  float4 v = *reinterpret_cast<const float4*>(&src[i]);
  dst[i + 0] = __float2bfloat16(v.x);
  dst[i + 1] = __float2bfloat16(v.y);
  dst[i + 2] = __float2bfloat16(v.z);
  dst[i + 3] = __float2bfloat16(v.w);
}

// ---------------------------------------------------------------------------
// Input GEMM (fp32): U[b,h,l] = sum_k X[b,l,k] * W[k,h] + bias[h]
// ---------------------------------------------------------------------------
__global__ __launch_bounds__(256) void k_ingemm(const float* __restrict__ X,
                                                const float* __restrict__ W,
                                                const float* __restrict__ bias,
                                                float* __restrict__ U) {
  __shared__ float At[32][132];
  __shared__ float Bt[32][132];
  int lt = blockIdx.x * 128;
  int ht = blockIdx.y * 128;
  int b  = blockIdx.z;
  int tid = threadIdx.x;
  int tr = tid >> 4, tc = tid & 15;
  int r0 = tr * 4, c0 = tc * 4;
  float acc[2][2][4][4] = {};
  for (int kt = 0; kt < INP; kt += 32) {
    for (int i = tid; i < 32 * 128; i += 256) {
      int k = i >> 7, r = i & 127;
      At[k][r] = W[(size_t)(kt + k) * HH + ht + r];
    }
    {
      int k4 = (tid & 7) * 4;
      int cb = tid >> 3;
      #pragma unroll
      for (int p = 0; p < 4; ++p) {
        int c = cb + 32 * p;
        const float4 v = *reinterpret_cast<const float4*>(
            &X[((size_t)b * LL + lt + c) * INP + kt + k4]);
        Bt[k4 + 0][c] = v.x; Bt[k4 + 1][c] = v.y;
        Bt[k4 + 2][c] = v.z; Bt[k4 + 3][c] = v.w;
      }
    }
    __syncthreads();
    #pragma unroll
    for (int k = 0; k < 32; ++k) {
      float4 a0 = *reinterpret_cast<const float4*>(&At[k][r0]);
      float4 a1 = *reinterpret_cast<const float4*>(&At[k][r0 + 64]);
      float4 b0 = *reinterpret_cast<const float4*>(&Bt[k][c0]);
      float4 b1 = *reinterpret_cast<const float4*>(&Bt[k][c0 + 64]);
      float ar[2][4] = {{a0.x, a0.y, a0.z, a0.w}, {a1.x, a1.y, a1.z, a1.w}};
      float bc[2][4] = {{b0.x, b0.y, b0.z, b0.w}, {b1.x, b1.y, b1.z, b1.w}};
      #pragma unroll
      for (int p = 0; p < 2; ++p)
        #pragma unroll
        for (int q = 0; q < 2; ++q)
          #pragma unroll
          for (int i = 0; i < 4; ++i)
            #pragma unroll
            for (int j = 0; j < 4; ++j)
              acc[p][q][i][j] = fmaf(ar[p][i], bc[q][j], acc[p][q][i][j]);
    }
    __syncthreads();
  }
  #pragma unroll
  for (int p = 0; p < 2; ++p)
    #pragma unroll
    for (int i = 0; i < 4; ++i) {
      int h = ht + r0 + p * 64 + i;
      float bv = bias[h];
      #pragma unroll
      for (int q = 0; q < 2; ++q) {
        float4 o;
        o.x = acc[p][q][i][0] + bv;
        o.y = acc[p][q][i][1] + bv;
        o.z = acc[p][q][i][2] + bv;
        o.w = acc[p][q][i][3] + bv;
        *reinterpret_cast<float4*>(&U[((size_t)b * HH + h) * LL + lt + c0 + q * 64]) = o;
      }
    }
}

// ---------------------------------------------------------------------------
// Chunk-parallel S4D scan. One 64-lane wave per row (b,h); block = 4 rows.
// T=16, C=128 chunks; lane owns chunks 2*lane, 2*lane+1 (l in [32*lane, 32*lane+32)).
// Per mode n: Z = sum_t w^{15-t} u[t] per chunk; Kogge-Stone prefix over chunk
// pairs (ratio w^32); carries S; y_t += Re((c2*w*S) * w^t). Then 16-tap FIR
// with K[d], + D*u, GELU, write bf16 Y[b][h][l].
// ---------------------------------------------------------------------------
__global__ __launch_bounds__(256) void k_scan(const float* __restrict__ U,
                                              __hip_bfloat16* __restrict__ Ybf,
                                              const float* __restrict__ Vtab,
                                              const float* __restrict__ Ktab,
                                              const float* __restrict__ P,
                                              const float* __restrict__ Dp) {
  int t = threadIdx.x;
  int lane = t & 63;
  int row = blockIdx.x * 4 + (t >> 6);     // b_local*H + h
  int h = row & (HH - 1);
  const float* urow = U + (size_t)row * LL;

  float u[32], y[32];
  {
    const float4* up4 = reinterpret_cast<const float4*>(urow + 32 * lane);
    #pragma unroll
    for (int i = 0; i < 8; ++i) {
      float4 v = up4[i];
      u[4 * i + 0] = v.x; u[4 * i + 1] = v.y;
      u[4 * i + 2] = v.z; u[4 * i + 3] = v.w;
    }
  }
  #pragma unroll
  for (int i = 0; i < 32; ++i) y[i] = 0.0f;

  const float4* vbase = reinterpret_cast<const float4*>(Vtab + (size_t)h * NN2 * 32);
  const float4* pbase = reinterpret_cast<const float4*>(P) + (size_t)h * NN2;

  #pragma unroll 1
  for (int n = 0; n < NN2; ++n) {
    float4 pv[8];
    #pragma unroll
    for (int i = 0; i < 8; ++i) pv[i] = vbase[n * 8 + i];
    float4 pq = pbase[n];
    float w_r = pq.x, w_i = pq.y, c2r = pq.z, c2i = pq.w;

    // phase A: chunk sums (u real -> 2 FMA per (t,chunk))
    float Zar = 0.f, Zai = 0.f, Zbr = 0.f, Zbi = 0.f;
    #pragma unroll
    for (int tt = 0; tt < 16; ++tt) {
      int d = 15 - tt;
      float pr = (d & 1) ? pv[d >> 1].z : pv[d >> 1].x;
      float pi = (d & 1) ? pv[d >> 1].w : pv[d >> 1].y;
      Zar = fmaf(pr, u[tt], Zar);      Zai = fmaf(pi, u[tt], Zai);
      Zbr = fmaf(pr, u[16 + tt], Zbr); Zbi = fmaf(pi, u[16 + tt], Zbi);
    }
    // w16 = w^15 * w ; w32 = w16^2
    float w15r = pv[7].z, w15i = pv[7].w;
    float w16r = w15r * w_r - w15i * w_i;
    float w16i = w15r * w_i + w15i * w_r;
    float mr = w16r * w16r - w16i * w16i;
    float mi = 2.0f * w16r * w16i;
    // pair summary: Zp = w16*Za + Zb  (s_end of chunk 2*lane+1 given zero carry)
    float Ppr = fmaf(w16r, Zar, fmaf(-w16i, Zai, Zbr));
    float Ppi = fmaf(w16r, Zai, fmaf(w16i, Zar, Zbi));
    // Kogge-Stone inclusive scan over 64 lanes, ratio w32 (squared each round)
    #pragma unroll
    for (int k = 1; k <= 32; k <<= 1) {
      float qr = __shfl_up(Ppr, (unsigned)k);
      float qi = __shfl_up(Ppi, (unsigned)k);
      if (lane < k) { qr = 0.f; qi = 0.f; }
      Ppr = fmaf(mr, qr, fmaf(-mi, qi, Ppr));
      Ppi = fmaf(mr, qi, fmaf(mi, qr, Ppi));
      if (k < 32) {
        float tmr = mr * mr - mi * mi;
        mi = 2.0f * mr * mi;
        mr = tmr;
      }
    }
    // carries: S_A = s_end[2*lane-1] ; S_B = w16*S_A + Za
    float SAr = __shfl_up(Ppr, 1u), SAi = __shfl_up(Ppi, 1u);
    if (lane == 0) { SAr = 0.f; SAi = 0.f; }
    float SBr = fmaf(w16r, SAr, fmaf(-w16i, SAi, Zar));
    float SBi = fmaf(w16r, SAi, fmaf(w16i, SAr, Zai));
    // a = c2 * w * S  for each chunk
    float wsr = SAr * w_r - SAi * w_i, wsi = SAr * w_i + SAi * w_r;
    float aAr = c2r * wsr - c2i * wsi, aAi = c2r * wsi + c2i * wsr;
    wsr = SBr * w_r - SBi * w_i; wsi = SBr * w_i + SBi * w_r;
    float aBr = c2r * wsr - c2i * wsi, aBi = c2r * wsi + c2i * wsr;
    // phase C: y_t += Re(a * w^t)
    #pragma unroll
    for (int tt = 0; tt < 16; ++tt) {
      float pr = (tt & 1) ? pv[tt >> 1].z : pv[tt >> 1].x;
      float pi = (tt & 1) ? pv[tt >> 1].w : pv[tt >> 1].y;
      y[tt]      = fmaf(aAr, pr, fmaf(-aAi, pi, y[tt]));
      y[16 + tt] = fmaf(aBr, pr, fmaf(-aBi, pi, y[16 + tt]));
    }
  }

  // FIR: y_t += sum_{j<=t} K[t-j] * u_chunk[j]
  float kk[16];
  {
    const float4* kb = reinterpret_cast<const float4*>(Ktab + (size_t)h * 16);
    #pragma unroll
    for (int i = 0; i < 4; ++i) {
      float4 v = kb[i];
      kk[4 * i + 0] = v.x; kk[4 * i + 1] = v.y;
      kk[4 * i + 2] = v.z; kk[4 * i + 3] = v.w;
    }
  }
  #pragma unroll
  for (int j = 0; j < 16; ++j)
    #pragma unroll
    for (int tt = 15; tt >= 0; --tt) {
      if (tt < j) break;
      float kv = kk[tt - j];
      y[tt]      = fmaf(kv, u[j], y[tt]);
      y[16 + tt] = fmaf(kv, u[16 + j], y[16 + tt]);
    }

  float Dv = Dp[h];
  unsigned int words[16];
  #pragma unroll
  for (int i = 0; i < 16; ++i) {
    float v0 = gelu_erf(y[2 * i]     + Dv * u[2 * i]);
    float v1 = gelu_erf(y[2 * i + 1] + Dv * u[2 * i + 1]);
    words[i] = (unsigned int)bf16bits(v0) | ((unsigned int)bf16bits(v1) << 16);
  }
  uint4* dst = reinterpret_cast<uint4*>(Ybf + (size_t)row * LL + 32 * lane);
  #pragma unroll
  for (int i = 0; i < 4; ++i)
    dst[i] = make_uint4(words[4 * i], words[4 * i + 1], words[4 * i + 2], words[4 * i + 3]);
}

// ---------------------------------------------------------------------------
// Transpose bf16 [b][h][l] -> [b][l][h].  Tile 32h x 128l per block.
// ---------------------------------------------------------------------------
__global__ __launch_bounds__(256) void k_transpose(const __hip_bfloat16* __restrict__ src,
                                                   __hip_bfloat16* __restrict__ dst) {
  __shared__ short lds[32][132];
  int t = threadIdx.x;
  int l0 = blockIdx.x * 128;
  int h0 = blockIdx.y * 32;
  int b  = blockIdx.z;
  const short* S = (const short*)(src + (size_t)b * HH * LL);
  short* D = (short*)(dst + (size_t)b * LL * HH);
  {
    int h = t >> 3, s0 = (t & 7) * 2;
    #pragma unroll
    for (int s = s0; s < s0 + 2; ++s) {
      float4 v = *reinterpret_cast<const float4*>(&S[(size_t)(h0 + h) * LL + l0 + s * 8]);
      *reinterpret_cast<float2*>(&lds[h][s * 8])     = make_float2(v.x, v.y);
      *reinterpret_cast<float2*>(&lds[h][s * 8 + 4]) = make_float2(v.z, v.w);
    }
  }
  __syncthreads();
  {
    int l = t >> 1, half = t & 1;
    unsigned int w[8];
    #pragma unroll
    for (int j = 0; j < 8; ++j) {
      unsigned short s0 = (unsigned short)lds[half * 16 + 2 * j][l];
      unsigned short s1 = (unsigned short)lds[half * 16 + 2 * j + 1][l];
      w[j] = (unsigned int)s0 | ((unsigned int)s1 << 16);
    }
    uint4* dp = reinterpret_cast<uint4*>(&D[(size_t)(l0 + l) * HH + h0 + half * 16]);
    dp[0] = make_uint4(w[0], w[1], w[2], w[3]);
    dp[1] = make_uint4(w[4], w[5], w[6], w[7]);
  }
}

// ---------------------------------------------------------------------------
// conv1x1 + GLU, bf16 MFMA 16x16x32 (unchanged from round 4).
// ---------------------------------------------------------------------------
__global__ __launch_bounds__(256) void k_conv(const __hip_bfloat16* __restrict__ Ytb,
                                              const __hip_bfloat16* __restrict__ CWb,
                                              const float* __restrict__ CB,
                                              float* __restrict__ U) {
  __shared__ short Alds[128 * 64];
  __shared__ short Blds[128 * 64];
  int lt = blockIdx.x * 128;
  int ot = blockIdx.y * 64;
  int b  = blockIdx.z;
  int t = threadIdx.x;
  int wid = t >> 6, lane = t & 63;
  int wr = wid >> 1, wc = wid & 1;
  int l15 = lane & 15, l4 = lane >> 4;
  f32x4 zero = {0.f, 0.f, 0.f, 0.f};
  f32x4 accA[2][4], accG[2][4];
  #pragma unroll
  for (int m = 0; m < 2; ++m)
    #pragma unroll
    for (int n = 0; n < 4; ++n) { accA[m][n] = zero; accG[m][n] = zero; }

  const char* Yb = (const char*)(Ytb + (size_t)b * LL * HH);
  const char* Wb = (const char*)CWb;

  for (int kt = 0; kt < HH; kt += 64) {
    #pragma unroll
    for (int it = 0; it < 4; ++it) {
      int d = 16 * (t + 256 * it);
      int rowl = d >> 7, cb = d & 127;
      int orow = (rowl < 64) ? (ot + rowl) : (448 + ot + rowl);
      gload16(Wb + (size_t)orow * 1024 + kt * 2 + (cb ^ ((rowl & 7) << 4)),
              (char*)Alds + d);
    }
    #pragma unroll
    for (int it = 0; it < 4; ++it) {
      int d = 16 * (t + 256 * it);
      int rowl = d >> 7, cb = d & 127;
      gload16(Yb + ((size_t)(lt + rowl) * 512 + kt) * 2 + (cb ^ ((rowl & 7) << 4)),
              (char*)Blds + d);
    }
    __syncthreads();
    #pragma unroll
    for (int ks = 0; ks < 2; ++ks) {
      short8 af[4], bf[4];
      #pragma unroll
      for (int m = 0; m < 4; ++m) {
        int mrow = ((m < 2) ? (wr * 32 + m * 16) : (64 + wr * 32 + (m - 2) * 16)) + l15;
        int colb = (ks * 64 + 16 * l4) ^ ((mrow & 7) << 4);
        af[m] = *reinterpret_cast<const short8*>((const char*)Alds + mrow * 128 + colb);
      }
      #pragma unroll
      for (int n = 0; n < 4; ++n) {
        int nrow = wc * 64 + n * 16 + l15;
        int colb = (ks * 64 + 16 * l4) ^ ((nrow & 7) << 4);
        bf[n] = *reinterpret_cast<const short8*>((const char*)Blds + nrow * 128 + colb);
      }
      #pragma unroll
      for (int m = 0; m < 2; ++m)
        #pragma unroll
        for (int n = 0; n < 4; ++n) {
          accA[m][n] = __builtin_amdgcn_mfma_f32_16x16x32_bf16(af[m], bf[n], accA[m][n], 0, 0, 0);
          accG[m][n] = __builtin_amdgcn_mfma_f32_16x16x32_bf16(af[m + 2], bf[n], accG[m][n], 0, 0, 0);
        }
    }
    __syncthreads();
  }
  #pragma unroll
  for (int m = 0; m < 2; ++m) {
    #pragma unroll
    for (int r = 0; r < 4; ++r) {
      int rowl = wr * 32 + m * 16 + l4 * 4 + r;
      float ba = CB[ot + rowl];
      float bg = CB[512 + ot + rowl];
      float* urow_ = U + ((size_t)b * HH + ot + rowl) * LL + lt + wc * 64;
      #pragma unroll
      for (int n = 0; n < 4; ++n) {
        float a = accA[m][n][r] + ba;
        float g = accG[m][n][r] + bg;
        urow_[n * 16 + l15] = a * sigmoidf_(g);
      }
    }
  }
}

// ---------------------------------------------------------------------------
// Output projection (fp32 out).
// ---------------------------------------------------------------------------
__global__ __launch_bounds__(256) void k_outgemm(const float* __restrict__ U,
                                                 const float* __restrict__ Wo,
                                                 const float* __restrict__ bo,
                                                 float* __restrict__ out) {
  int bl = blockIdx.x * 256 + threadIdx.x;
  int b = bl >> 11, l = bl & (LL - 1);
  float a0 = 0.0f, a1 = 0.0f;
  const float* up = U + (size_t)b * HH * LL + l;
  #pragma unroll 4
  for (int h = 0; h < HH; ++h) {
    float v = up[(size_t)h * LL];
    a0 = fmaf(v, Wo[h * 2 + 0], a0);
    a1 = fmaf(v, Wo[h * 2 + 1], a1);
  }
  out[(size_t)bl * 2 + 0] = a0 + bo[0];
  out[(size_t)bl * 2 + 1] = a1 + bo[1];
}

extern "C" void kernel_launch(void* const* d_in, const int* in_sizes, int n_in,
                              void* d_out, int out_size, void* d_ws, size_t ws_size,
                              hipStream_t stream) {
  const float* X      = (const float*)d_in[0];
  const float* Win    = (const float*)d_in[1];
  const float* bin    = (const float*)d_in[2];
  const float* log_dt = (const float*)d_in[3];
  const float* Cri    = (const float*)d_in[4];
  const float* lAr    = (const float*)d_in[5];
  const float* Aim    = (const float*)d_in[6];
  const float* Dp     = (const float*)d_in[7];
  const float* CW     = (const float*)d_in[8];
  const float* CB     = (const float*)d_in[9];
  const float* Wo     = (const float*)d_in[10];
  const float* bo     = (const float*)d_in[11];
  float* out = (float*)d_out;

  // ws: [P 256K f][CWb 1M f][Vtab 2M f][Kt 32K f][per-G: U 1M f, Ybf .5M f, Yt .5M f]
  const size_t Pfloats  = (size_t)NNL * HH * NN2 * 4;      // 262144
  const size_t CWfloats = (size_t)NNL * 2 * HH * HH / 2;   // 1048576
  const size_t Vfloats  = (size_t)NNL * HH * NN2 * 32;     // 2097152
  const size_t Kfloats  = (size_t)NNL * HH * 16;           // 32768
  const size_t HL       = (size_t)HH * LL;                 // 1048576

  float* P    = (float*)d_ws;
  __hip_bfloat16* CWb = (__hip_bfloat16*)(P + Pfloats);
  float* Vtab = P + Pfloats + CWfloats;
  float* Ktab = Vtab + Vfloats;
  size_t head = Pfloats + CWfloats + Vfloats + Kfloats;

  size_t ws_floats = ws_size / sizeof(float);
  size_t avail = (ws_floats > head) ? (ws_floats - head) : 0;
  int G = (int)(avail / (2 * HL));
  if (G > BB) G = BB;
  if (G < 1) G = 1;

  float* U = P + head;
  __hip_bfloat16* Ybf = (__hip_bfloat16*)(U + (size_t)G * HL);
  __hip_bfloat16* Yt  = Ybf + (size_t)G * HL;

  k_params<<<(NNL * HH * NN2 + 255) / 256, 256, 0, stream>>>(log_dt, Cri, lAr, Aim, P);
  k_tables<<<NNL * HH / 8, 256, 0, stream>>>(P, Vtab, Ktab);
  k_tobf16<<<(NNL * 2 * HH * HH) / 1024, 256, 0, stream>>>(CW, CWb, NNL * 2 * HH * HH);

  for (int b0 = 0; b0 < BB; b0 += G) {
    int g = (BB - b0 < G) ? (BB - b0) : G;
    k_ingemm<<<dim3(LL / 128, HH / 128, g), 256, 0, stream>>>(
        X + (size_t)b0 * LL * INP, Win, bin, U);
    for (int layer = 0; layer < NNL; ++layer) {
      k_scan<<<g * (HH / 4), 256, 0, stream>>>(
          U, Ybf,
          Vtab + (size_t)layer * HH * NN2 * 32,
          Ktab + (size_t)layer * HH * 16,
          P + (size_t)layer * HH * NN2 * 4,
          Dp + (size_t)layer * HH);
      k_transpose<<<dim3(LL / 128, HH / 32, g), 256, 0, stream>>>(Ybf, Yt);
      k_conv<<<dim3(LL / 128, HH / 64, g), 256, 0, stream>>>(
          Yt, CWb + (size_t)layer * 2 * HH * HH, CB + (size_t)layer * 2 * HH, U);
    }
    k_outgemm<<<g * LL / 256, 256, 0, stream>>>(
        U, Wo, bo, out + (size_t)b0 * LL * OUTC);
  }
}

// Round 6
// 1602.293 us; speedup vs baseline: 4.6885x; 1.2063x over previous
//
#include <hip/hip_runtime.h>
#include <hip/hip_bf16.h>
#include <math.h>

#define BB 32
#define LL 2048
#define INP 192
#define OUTC 2
#define HH 512
#define NN2 32
#define NNL 4
#define VSTRIDE 72   // floats per (h, mode) table record

using short8 = __attribute__((ext_vector_type(8))) short;
using f32x4  = __attribute__((ext_vector_type(4))) float;
using f32x2  = __attribute__((ext_vector_type(2))) float;

__device__ __forceinline__ float gelu_erf(float x) {
  return 0.5f * x * (1.0f + erff(x * 0.70710678118654752f));
}
__device__ __forceinline__ float sigmoidf_(float x) {
  return 1.0f / (1.0f + expf(-x));
}
__device__ __forceinline__ unsigned short bf16bits(float x) {
  __hip_bfloat16 b = __float2bfloat16(x);
  return __builtin_bit_cast(unsigned short, b);
}
__device__ __forceinline__ void gload16(const void* gsrc, void* ldst) {
  __builtin_amdgcn_global_load_lds(
      (const __attribute__((address_space(1))) void*)gsrc,
      (__attribute__((address_space(3))) void*)ldst, 16, 0, 0);
}

// ---------------------------------------------------------------------------
// P[NL][H][N2][4] = {w_re, w_im, c2_re, c2_im}
// ---------------------------------------------------------------------------
__global__ __launch_bounds__(256) void k_params(const float* __restrict__ log_dt,
                                                const float* __restrict__ Cri,
                                                const float* __restrict__ lAr,
                                                const float* __restrict__ Aim,
                                                float* __restrict__ P) {
  int idx = blockIdx.x * 256 + threadIdx.x;
  if (idx >= NNL * HH * NN2) return;
  float dt  = expf(log_dt[idx / NN2]);
  float Are = -expf(lAr[idx]);
  float Aimv = Aim[idx];
  float dre = Are * dt, dim = Aimv * dt;
  float er = expf(dre);
  float wrv = er * cosf(dim);
  float wiv = er * sinf(dim);
  float Er = wrv - 1.0f, Ei = wiv;
  float den = Are * Are + Aimv * Aimv;
  float Fr = (Er * Are + Ei * Aimv) / den;
  float Fi = (Ei * Are - Er * Aimv) / den;
  float Cre = Cri[idx * 2 + 0], Cim = Cri[idx * 2 + 1];
  P[idx * 4 + 0] = wrv;
  P[idx * 4 + 1] = wiv;
  P[idx * 4 + 2] = 2.0f * (Cre * Fr - Cim * Fi);
  P[idx * 4 + 3] = 2.0f * (Cre * Fi + Cim * Fr);
}

// ---------------------------------------------------------------------------
// Scan tables. Per (layer,h,n) record of VSTRIDE floats:
//  [0..31]  interleaved (re,im) of w^d, d=0..15   (phase A)
//  [32..47] re(w^d)  d=0..15                      (phase C)
//  [48..63] im(w^d)  d=0..15
//  [64,65]  w^16     [66,67] w^32     [68,69] c2*w   [70,71] pad
// Kt[(layer,h)][d] = Re sum_n c2_n w_n^d  (FIR taps).
// ---------------------------------------------------------------------------
__global__ __launch_bounds__(256) void k_tables(const float* __restrict__ P,
                                                float* __restrict__ V,
                                                float* __restrict__ Kt) {
  int t = threadIdx.x;
  int n = t & 31;
  int inst = blockIdx.x * 8 + (t >> 5);     // (layer*H + h)
  size_t idx = (size_t)inst * NN2 + n;
  float4 pq = reinterpret_cast<const float4*>(P)[idx];
  float wr = pq.x, wi = pq.y, c2r = pq.z, c2i = pq.w;
  float* vr = V + idx * VSTRIDE;
  float pr = 1.0f, pi = 0.0f;
  for (int d = 0; d < 16; ++d) {
    vr[2 * d] = pr; vr[2 * d + 1] = pi;
    vr[32 + d] = pr; vr[48 + d] = pi;
    float kp = c2r * pr - c2i * pi;
    #pragma unroll
    for (int k = 1; k < 32; k <<= 1) kp += __shfl_xor(kp, k, 32);
    if (n == 0) Kt[(size_t)inst * 16 + d] = kp;
    float nr = pr * wr - pi * wi;
    pi = pr * wi + pi * wr;
    pr = nr;
  }
  // pr,pi now = w^16
  vr[64] = pr; vr[65] = pi;
  vr[66] = pr * pr - pi * pi;
  vr[67] = 2.0f * pr * pi;
  vr[68] = c2r * wr - c2i * wi;
  vr[69] = c2r * wi + c2i * wr;
  vr[70] = 0.0f; vr[71] = 0.0f;
}

// ---------------------------------------------------------------------------
// fp32 -> bf16 convert (CW weights).
// ---------------------------------------------------------------------------
__global__ __launch_bounds__(256) void k_tobf16(const float* __restrict__ src,
                                                __hip_bfloat16* __restrict__ dst,
                                                int n) {
  int i = (blockIdx.x * 256 + threadIdx.x) * 4;
  if (i >= n) return;
  float4 v = *reinterpret_cast<const float4*>(&src[i]);
  dst[i + 0] = __float2bfloat16(v.x);
  dst[i + 1] = __float2bfloat16(v.y);
  dst[i + 2] = __float2bfloat16(v.z);
  dst[i + 3] = __float2bfloat16(v.w);
}

// ---------------------------------------------------------------------------
// Input GEMM (fp32): U[b,h,l] = sum_k X[b,l,k] * W[k,h] + bias[h]
// ---------------------------------------------------------------------------
__global__ __launch_bounds__(256) void k_ingemm(const float* __restrict__ X,
                                                const float* __restrict__ W,
                                                const float* __restrict__ bias,
                                                float* __restrict__ U) {
  __shared__ float At[32][132];
  __shared__ float Bt[32][132];
  int lt = blockIdx.x * 128;
  int ht = blockIdx.y * 128;
  int b  = blockIdx.z;
  int tid = threadIdx.x;
  int tr = tid >> 4, tc = tid & 15;
  int r0 = tr * 4, c0 = tc * 4;
  float acc[2][2][4][4] = {};
  for (int kt = 0; kt < INP; kt += 32) {
    for (int i = tid; i < 32 * 128; i += 256) {
      int k = i >> 7, r = i & 127;
      At[k][r] = W[(size_t)(kt + k) * HH + ht + r];
    }
    {
      int k4 = (tid & 7) * 4;
      int cb = tid >> 3;
      #pragma unroll
      for (int p = 0; p < 4; ++p) {
        int c = cb + 32 * p;
        const float4 v = *reinterpret_cast<const float4*>(
            &X[((size_t)b * LL + lt + c) * INP + kt + k4]);
        Bt[k4 + 0][c] = v.x; Bt[k4 + 1][c] = v.y;
        Bt[k4 + 2][c] = v.z; Bt[k4 + 3][c] = v.w;
      }
    }
    __syncthreads();
    #pragma unroll
    for (int k = 0; k < 32; ++k) {
      float4 a0 = *reinterpret_cast<const float4*>(&At[k][r0]);
      float4 a1 = *reinterpret_cast<const float4*>(&At[k][r0 + 64]);
      float4 b0 = *reinterpret_cast<const float4*>(&Bt[k][c0]);
      float4 b1 = *reinterpret_cast<const float4*>(&Bt[k][c0 + 64]);
      float ar[2][4] = {{a0.x, a0.y, a0.z, a0.w}, {a1.x, a1.y, a1.z, a1.w}};
      float bc[2][4] = {{b0.x, b0.y, b0.z, b0.w}, {b1.x, b1.y, b1.z, b1.w}};
      #pragma unroll
      for (int p = 0; p < 2; ++p)
        #pragma unroll
        for (int q = 0; q < 2; ++q)
          #pragma unroll
          for (int i = 0; i < 4; ++i)
            #pragma unroll
            for (int j = 0; j < 4; ++j)
              acc[p][q][i][j] = fmaf(ar[p][i], bc[q][j], acc[p][q][i][j]);
    }
    __syncthreads();
  }
  #pragma unroll
  for (int p = 0; p < 2; ++p)
    #pragma unroll
    for (int i = 0; i < 4; ++i) {
      int h = ht + r0 + p * 64 + i;
      float bv = bias[h];
      #pragma unroll
      for (int q = 0; q < 2; ++q) {
        float4 o;
        o.x = acc[p][q][i][0] + bv;
        o.y = acc[p][q][i][1] + bv;
        o.z = acc[p][q][i][2] + bv;
        o.w = acc[p][q][i][3] + bv;
        *reinterpret_cast<float4*>(&U[((size_t)b * HH + h) * LL + lt + c0 + q * 64]) = o;
      }
    }
}

// ---------------------------------------------------------------------------
// Chunk-parallel S4D scan, v2: wave-uniform scalar table (SGPR) + f32x2
// packed math. One wave per row; lane owns elems [32*lane, 32*lane+32) as
// two 16-chunks A,B. Per mode: chunk sums -> Kogge-Stone over chunk pairs
// (ratio w^32) -> carries -> y += Re(a w^t). Then FIR, D*u, GELU, bf16 out.
// ---------------------------------------------------------------------------
__global__ __launch_bounds__(256) void k_scan(const float* __restrict__ U,
                                              __hip_bfloat16* __restrict__ Ybf,
                                              const float* __restrict__ Vtab,
                                              const float* __restrict__ Ktab,
                                              const float* __restrict__ Dp) {
  int t = threadIdx.x;
  int lane = t & 63;
  int ru = __builtin_amdgcn_readfirstlane(blockIdx.x * 4 + (t >> 6));  // wave row
  int h = ru & (HH - 1);
  const float* vb = Vtab + (size_t)h * (NN2 * VSTRIDE);   // uniform base
  const float* kb = Ktab + (size_t)h * 16;                // uniform base
  const float* urow = U + (size_t)ru * LL;

  f32x2 u2[16], y2[16];
  {
    const float4* up4 = reinterpret_cast<const float4*>(urow + 32 * lane);
    #pragma unroll
    for (int i = 0; i < 8; ++i) {
      float4 v = up4[i];
      u2[2 * i]     = f32x2{v.x, v.y};
      u2[2 * i + 1] = f32x2{v.z, v.w};
    }
  }
  #pragma unroll
  for (int i = 0; i < 16; ++i) y2[i] = f32x2{0.f, 0.f};

  #pragma unroll 1
  for (int n = 0; n < NN2; ++n) {
    const float* vr = vb + n * VSTRIDE;   // uniform; imm-offset s_loads below
    // phase A: Z = sum_t w^{15-t} u[t]  (packed complex accumulate)
    f32x2 ZA = {0.f, 0.f}, ZB = {0.f, 0.f};
    #pragma unroll
    for (int tt = 0; tt < 16; ++tt) {
      int d = 15 - tt;
      f32x2 wv = *reinterpret_cast<const f32x2*>(vr + 2 * d);
      float uA = u2[tt >> 1][tt & 1];
      float uB = u2[8 + (tt >> 1)][tt & 1];
      ZA = wv * f32x2{uA, uA} + ZA;
      ZB = wv * f32x2{uB, uB} + ZB;
    }
    f32x2 w16 = *reinterpret_cast<const f32x2*>(vr + 64);
    f32x2 w32 = *reinterpret_cast<const f32x2*>(vr + 66);
    f32x2 c2w = *reinterpret_cast<const f32x2*>(vr + 68);
    // pair summary: Pp = w16*ZA + ZB
    float Ppr = fmaf(w16[0], ZA[0], fmaf(-w16[1], ZA[1], ZB[0]));
    float Ppi = fmaf(w16[0], ZA[1], fmaf(w16[1], ZA[0], ZB[1]));
    // Kogge-Stone inclusive scan, ratio w^32 squared each round
    float mr = w32[0], mi = w32[1];
    #pragma unroll
    for (int k = 1; k <= 32; k <<= 1) {
      float qr = __shfl_up(Ppr, (unsigned)k);
      float qi = __shfl_up(Ppi, (unsigned)k);
      if (lane < k) { qr = 0.f; qi = 0.f; }
      Ppr = fmaf(mr, qr, fmaf(-mi, qi, Ppr));
      Ppi = fmaf(mr, qi, fmaf(mi, qr, Ppi));
      if (k < 32) {
        float tmr = mr * mr - mi * mi;
        mi = 2.0f * mr * mi;
        mr = tmr;
      }
    }
    // carries
    float SAr = __shfl_up(Ppr, 1u), SAi = __shfl_up(Ppi, 1u);
    if (lane == 0) { SAr = 0.f; SAi = 0.f; }
    float SBr = fmaf(w16[0], SAr, fmaf(-w16[1], SAi, ZA[0]));
    float SBi = fmaf(w16[0], SAi, fmaf(w16[1], SAr, ZA[1]));
    // a = (c2*w) * S
    float aAr = c2w[0] * SAr - c2w[1] * SAi;
    float aAi = c2w[0] * SAi + c2w[1] * SAr;
    float aBr = c2w[0] * SBr - c2w[1] * SBi;
    float aBi = c2w[0] * SBi + c2w[1] * SBr;
    f32x2 aAr2 = {aAr, aAr}, naAi2 = {-aAi, -aAi};
    f32x2 aBr2 = {aBr, aBr}, naBi2 = {-aBi, -aBi};
    // phase C: y_t += Re(a * w^t), de-interleaved tables, packed pairs
    #pragma unroll
    for (int i = 0; i < 8; ++i) {
      f32x2 pr2 = *reinterpret_cast<const f32x2*>(vr + 32 + 2 * i);
      f32x2 pi2 = *reinterpret_cast<const f32x2*>(vr + 48 + 2 * i);
      y2[i]     = pr2 * aAr2 + y2[i];
      y2[i]     = pi2 * naAi2 + y2[i];
      y2[8 + i] = pr2 * aBr2 + y2[8 + i];
      y2[8 + i] = pi2 * naBi2 + y2[8 + i];
    }
  }

  // FIR: y[tt] += sum_{j<=tt} K[tt-j] * u[j] (per chunk), packed over tt-pairs
  float kk[16];
  #pragma unroll
  for (int d = 0; d < 16; ++d) kk[d] = kb[d];   // uniform -> SGPR
  #pragma unroll
  for (int j = 0; j < 16; ++j) {
    float uA = u2[j >> 1][j & 1];
    float uB = u2[8 + (j >> 1)][j & 1];
    f32x2 uA2 = {uA, uA}, uB2 = {uB, uB};
    if (j & 1) {
      int i0 = j >> 1;                 // boundary pair: only tt=j contributes
      y2[i0][1]     = fmaf(kk[0], uA, y2[i0][1]);
      y2[8 + i0][1] = fmaf(kk[0], uB, y2[8 + i0][1]);
      #pragma unroll
      for (int i = (j >> 1) + 1; i < 8; ++i) {
        f32x2 kp = {kk[2 * i - j], kk[2 * i + 1 - j]};
        y2[i]     = kp * uA2 + y2[i];
        y2[8 + i] = kp * uB2 + y2[8 + i];
      }
    } else {
      #pragma unroll
      for (int i = j >> 1; i < 8; ++i) {
        f32x2 kp = {kk[2 * i - j], kk[2 * i + 1 - j]};
        y2[i]     = kp * uA2 + y2[i];
        y2[8 + i] = kp * uB2 + y2[8 + i];
      }
    }
  }

  float Dv = Dp[h];
  unsigned int words[16];
  #pragma unroll
  for (int i = 0; i < 16; ++i) {
    float v0 = gelu_erf(fmaf(Dv, u2[i][0], y2[i][0]));
    float v1 = gelu_erf(fmaf(Dv, u2[i][1], y2[i][1]));
    words[i] = (unsigned int)bf16bits(v0) | ((unsigned int)bf16bits(v1) << 16);
  }
  uint4* dst = reinterpret_cast<uint4*>(Ybf + (size_t)ru * LL + 32 * lane);
  #pragma unroll
  for (int i = 0; i < 4; ++i)
    dst[i] = make_uint4(words[4 * i], words[4 * i + 1], words[4 * i + 2], words[4 * i + 3]);
}

// ---------------------------------------------------------------------------
// Transpose bf16 [b][h][l] -> [b][l][h].  Tile 32h x 128l per block.
// ---------------------------------------------------------------------------
__global__ __launch_bounds__(256) void k_transpose(const __hip_bfloat16* __restrict__ src,
                                                   __hip_bfloat16* __restrict__ dst) {
  __shared__ short lds[32][132];
  int t = threadIdx.x;
  int l0 = blockIdx.x * 128;
  int h0 = blockIdx.y * 32;
  int b  = blockIdx.z;
  const short* S = (const short*)(src + (size_t)b * HH * LL);
  short* D = (short*)(dst + (size_t)b * LL * HH);
  {
    int h = t >> 3, s0 = (t & 7) * 2;
    #pragma unroll
    for (int s = s0; s < s0 + 2; ++s) {
      float4 v = *reinterpret_cast<const float4*>(&S[(size_t)(h0 + h) * LL + l0 + s * 8]);
      *reinterpret_cast<float2*>(&lds[h][s * 8])     = make_float2(v.x, v.y);
      *reinterpret_cast<float2*>(&lds[h][s * 8 + 4]) = make_float2(v.z, v.w);
    }
  }
  __syncthreads();
  {
    int l = t >> 1, half = t & 1;
    unsigned int w[8];
    #pragma unroll
    for (int j = 0; j < 8; ++j) {
      unsigned short s0 = (unsigned short)lds[half * 16 + 2 * j][l];
      unsigned short s1 = (unsigned short)lds[half * 16 + 2 * j + 1][l];
      w[j] = (unsigned int)s0 | ((unsigned int)s1 << 16);
    }
    uint4* dp = reinterpret_cast<uint4*>(&D[(size_t)(l0 + l) * HH + h0 + half * 16]);
    dp[0] = make_uint4(w[0], w[1], w[2], w[3]);
    dp[1] = make_uint4(w[4], w[5], w[6], w[7]);
  }
}

// ---------------------------------------------------------------------------
// conv1x1 + GLU, bf16 MFMA 16x16x32.
// ---------------------------------------------------------------------------
__global__ __launch_bounds__(256) void k_conv(const __hip_bfloat16* __restrict__ Ytb,
                                              const __hip_bfloat16* __restrict__ CWb,
                                              const float* __restrict__ CB,
                                              float* __restrict__ U) {
  __shared__ short Alds[128 * 64];
  __shared__ short Blds[128 * 64];
  int lt = blockIdx.x * 128;
  int ot = blockIdx.y * 64;
  int b  = blockIdx.z;
  int t = threadIdx.x;
  int wid = t >> 6, lane = t & 63;
  int wr = wid >> 1, wc = wid & 1;
  int l15 = lane & 15, l4 = lane >> 4;
  f32x4 zero = {0.f, 0.f, 0.f, 0.f};
  f32x4 accA[2][4], accG[2][4];
  #pragma unroll
  for (int m = 0; m < 2; ++m)
    #pragma unroll
    for (int n = 0; n < 4; ++n) { accA[m][n] = zero; accG[m][n] = zero; }

  const char* Yb = (const char*)(Ytb + (size_t)b * LL * HH);
  const char* Wb = (const char*)CWb;

  for (int kt = 0; kt < HH; kt += 64) {
    #pragma unroll
    for (int it = 0; it < 4; ++it) {
      int d = 16 * (t + 256 * it);
      int rowl = d >> 7, cb = d & 127;
      int orow = (rowl < 64) ? (ot + rowl) : (448 + ot + rowl);
      gload16(Wb + (size_t)orow * 1024 + kt * 2 + (cb ^ ((rowl & 7) << 4)),
              (char*)Alds + d);
    }
    #pragma unroll
    for (int it = 0; it < 4; ++it) {
      int d = 16 * (t + 256 * it);
      int rowl = d >> 7, cb = d & 127;
      gload16(Yb + ((size_t)(lt + rowl) * 512 + kt) * 2 + (cb ^ ((rowl & 7) << 4)),
              (char*)Blds + d);
    }
    __syncthreads();
    #pragma unroll
    for (int ks = 0; ks < 2; ++ks) {
      short8 af[4], bf[4];
      #pragma unroll
      for (int m = 0; m < 4; ++m) {
        int mrow = ((m < 2) ? (wr * 32 + m * 16) : (64 + wr * 32 + (m - 2) * 16)) + l15;
        int colb = (ks * 64 + 16 * l4) ^ ((mrow & 7) << 4);
        af[m] = *reinterpret_cast<const short8*>((const char*)Alds + mrow * 128 + colb);
      }
      #pragma unroll
      for (int n = 0; n < 4; ++n) {
        int nrow = wc * 64 + n * 16 + l15;
        int colb = (ks * 64 + 16 * l4) ^ ((nrow & 7) << 4);
        bf[n] = *reinterpret_cast<const short8*>((const char*)Blds + nrow * 128 + colb);
      }
      #pragma unroll
      for (int m = 0; m < 2; ++m)
        #pragma unroll
        for (int n = 0; n < 4; ++n) {
          accA[m][n] = __builtin_amdgcn_mfma_f32_16x16x32_bf16(af[m], bf[n], accA[m][n], 0, 0, 0);
          accG[m][n] = __builtin_amdgcn_mfma_f32_16x16x32_bf16(af[m + 2], bf[n], accG[m][n], 0, 0, 0);
        }
    }
    __syncthreads();
  }
  #pragma unroll
  for (int m = 0; m < 2; ++m) {
    #pragma unroll
    for (int r = 0; r < 4; ++r) {
      int rowl = wr * 32 + m * 16 + l4 * 4 + r;
      float ba = CB[ot + rowl];
      float bg = CB[512 + ot + rowl];
      float* urow_ = U + ((size_t)b * HH + ot + rowl) * LL + lt + wc * 64;
      #pragma unroll
      for (int n = 0; n < 4; ++n) {
        float a = accA[m][n][r] + ba;
        float g = accG[m][n][r] + bg;
        urow_[n * 16 + l15] = a * sigmoidf_(g);
      }
    }
  }
}

// ---------------------------------------------------------------------------
// Output projection (fp32 out).
// ---------------------------------------------------------------------------
__global__ __launch_bounds__(256) void k_outgemm(const float* __restrict__ U,
                                                 const float* __restrict__ Wo,
                                                 const float* __restrict__ bo,
                                                 float* __restrict__ out) {
  int bl = blockIdx.x * 256 + threadIdx.x;
  int b = bl >> 11, l = bl & (LL - 1);
  float a0 = 0.0f, a1 = 0.0f;
  const float* up = U + (size_t)b * HH * LL + l;
  #pragma unroll 4
  for (int h = 0; h < HH; ++h) {
    float v = up[(size_t)h * LL];
    a0 = fmaf(v, Wo[h * 2 + 0], a0);
    a1 = fmaf(v, Wo[h * 2 + 1], a1);
  }
  out[(size_t)bl * 2 + 0] = a0 + bo[0];
  out[(size_t)bl * 2 + 1] = a1 + bo[1];
}

extern "C" void kernel_launch(void* const* d_in, const int* in_sizes, int n_in,
                              void* d_out, int out_size, void* d_ws, size_t ws_size,
                              hipStream_t stream) {
  const float* X      = (const float*)d_in[0];
  const float* Win    = (const float*)d_in[1];
  const float* bin    = (const float*)d_in[2];
  const float* log_dt = (const float*)d_in[3];
  const float* Cri    = (const float*)d_in[4];
  const float* lAr    = (const float*)d_in[5];
  const float* Aim    = (const float*)d_in[6];
  const float* Dp     = (const float*)d_in[7];
  const float* CW     = (const float*)d_in[8];
  const float* CB     = (const float*)d_in[9];
  const float* Wo     = (const float*)d_in[10];
  const float* bo     = (const float*)d_in[11];
  float* out = (float*)d_out;

  const size_t Pfloats  = (size_t)NNL * HH * NN2 * 4;          // 262144
  const size_t CWfloats = (size_t)NNL * 2 * HH * HH / 2;       // 1048576
  const size_t Vfloats  = (size_t)NNL * HH * NN2 * VSTRIDE;    // 4718592
  const size_t Kfloats  = (size_t)NNL * HH * 16;               // 32768
  const size_t HL       = (size_t)HH * LL;                     // 1048576

  float* P    = (float*)d_ws;
  __hip_bfloat16* CWb = (__hip_bfloat16*)(P + Pfloats);
  float* Vtab = P + Pfloats + CWfloats;
  float* Ktab = Vtab + Vfloats;
  size_t head = Pfloats + CWfloats + Vfloats + Kfloats;

  size_t ws_floats = ws_size / sizeof(float);
  size_t avail = (ws_floats > head) ? (ws_floats - head) : 0;
  int G = (int)(avail / (2 * HL));
  if (G > BB) G = BB;
  else if (G >= 16) G = 16;   // two balanced groups
  if (G < 1) G = 1;

  float* U = P + head;
  __hip_bfloat16* Ybf = (__hip_bfloat16*)(U + (size_t)G * HL);
  __hip_bfloat16* Yt  = Ybf + (size_t)G * HL;

  k_params<<<(NNL * HH * NN2 + 255) / 256, 256, 0, stream>>>(log_dt, Cri, lAr, Aim, P);
  k_tables<<<NNL * HH / 8, 256, 0, stream>>>(P, Vtab, Ktab);
  k_tobf16<<<(NNL * 2 * HH * HH) / 1024, 256, 0, stream>>>(CW, CWb, NNL * 2 * HH * HH);

  for (int b0 = 0; b0 < BB; b0 += G) {
    int g = (BB - b0 < G) ? (BB - b0) : G;
    k_ingemm<<<dim3(LL / 128, HH / 128, g), 256, 0, stream>>>(
        X + (size_t)b0 * LL * INP, Win, bin, U);
    for (int layer = 0; layer < NNL; ++layer) {
      k_scan<<<g * (HH / 4), 256, 0, stream>>>(
          U, Ybf,
          Vtab + (size_t)layer * HH * NN2 * VSTRIDE,
          Ktab + (size_t)layer * HH * 16,
          Dp + (size_t)layer * HH);
      k_transpose<<<dim3(LL / 128, HH / 32, g), 256, 0, stream>>>(Ybf, Yt);
      k_conv<<<dim3(LL / 128, HH / 64, g), 256, 0, stream>>>(
          Yt, CWb + (size_t)layer * 2 * HH * HH, CB + (size_t)layer * 2 * HH, U);
    }
    k_outgemm<<<g * LL / 256, 256, 0, stream>>>(
        U, Wo, bo, out + (size_t)b0 * LL * OUTC);
  }
}

// Round 7
// 1324.749 us; speedup vs baseline: 5.6708x; 1.2095x over previous
//
#include <hip/hip_runtime.h>
#include <hip/hip_bf16.h>
#include <math.h>

#define BB 32
#define LL 2048
#define INP 192
#define OUTC 2
#define HH 512
#define NN2 32
#define NNL 4
#define TABB 32768   // bytes of table per (layer,h)

using short8 = __attribute__((ext_vector_type(8))) short;
using f32x4  = __attribute__((ext_vector_type(4))) float;
using f32x2  = __attribute__((ext_vector_type(2))) float;

__device__ __forceinline__ float sigmoidf_(float x) {
  return 1.0f / (1.0f + expf(-x));
}
__device__ __forceinline__ unsigned short bf16bits(float x) {
  __hip_bfloat16 b = __float2bfloat16(x);
  return __builtin_bit_cast(unsigned short, b);
}
__device__ __forceinline__ float bfval(unsigned short b) {
  unsigned int u = (unsigned int)b << 16;
  return __builtin_bit_cast(float, u);
}
// Abramowitz-Stegun 7.1.26 erf (max err 1.5e-7) based exact-GELU
__device__ __forceinline__ float gelu_fast(float x) {
  float s = x * 0.70710678118654752f;
  float ax = fabsf(s);
  float tt = 1.0f / fmaf(0.3275911f, ax, 1.0f);
  float p = fmaf(1.061405429f, tt, -1.453152027f);
  p = fmaf(p, tt, 1.421413741f);
  p = fmaf(p, tt, -0.284496736f);
  p = fmaf(p, tt, 0.254829592f);
  float e = __expf(-s * s);
  float er = 1.0f - p * tt * e;
  er = copysignf(er, s);
  return 0.5f * x * (1.0f + er);
}
__device__ __forceinline__ void gload16(const void* gsrc, void* ldst) {
  __builtin_amdgcn_global_load_lds(
      (const __attribute__((address_space(1))) void*)gsrc,
      (__attribute__((address_space(3))) void*)ldst, 16, 0, 0);
}

// ---------------------------------------------------------------------------
// P[NL][H][N2][4] = {w_re, w_im, c2_re, c2_im}
// ---------------------------------------------------------------------------
__global__ __launch_bounds__(256) void k_params(const float* __restrict__ log_dt,
                                                const float* __restrict__ Cri,
                                                const float* __restrict__ lAr,
                                                const float* __restrict__ Aim,
                                                float* __restrict__ P) {
  int idx = blockIdx.x * 256 + threadIdx.x;
  if (idx >= NNL * HH * NN2) return;
  float dt  = expf(log_dt[idx / NN2]);
  float Are = -expf(lAr[idx]);
  float Aimv = Aim[idx];
  float dre = Are * dt, dim = Aimv * dt;
  float er = expf(dre);
  float wrv = er * cosf(dim);
  float wiv = er * sinf(dim);
  float Er = wrv - 1.0f, Ei = wiv;
  float den = Are * Are + Aimv * Aimv;
  float Fr = (Er * Are + Ei * Aimv) / den;
  float Fi = (Ei * Are - Er * Aimv) / den;
  float Cre = Cri[idx * 2 + 0], Cim = Cri[idx * 2 + 1];
  P[idx * 4 + 0] = wrv;
  P[idx * 4 + 1] = wiv;
  P[idx * 4 + 2] = 2.0f * (Cre * Fr - Cim * Fi);
  P[idx * 4 + 3] = 2.0f * (Cre * Fi + Cim * Fr);
}

// ---------------------------------------------------------------------------
// Build per-(layer,h) MFMA fragment tables (split bf16 hi/lo) + scan tables.
// Byte layout per lh (TABB = 32 KB):
//   0     WAhi[4 frags: mt*2+reim][lane][8 bf16]   A of phase A: A[n,t]=w_n^{31-t}
//   4096  WAlo
//   8192  WChi[4: mtT*2+kt][lane][8]   A' of phase C: [t, k=8g+j]:
//           j<4 -> re(w_{kt*16+4g+j}^t), j>=4 -> -im(w^t)
//   12288 WClo
//   16384 FIRhi[2: mtT][lane][8]       K[t-j] lower-tri (32-tap FIR)
//   18432 FIRlo
//   20480 PL[8 slots][64 lanes][6 f32] {w32, w32^m, c2*w}   (24 B each)
// One block of 64 threads per lh; threads 0..31 own mode n.
// ---------------------------------------------------------------------------
__global__ __launch_bounds__(64) void k_tables(const float* __restrict__ P,
                                               char* __restrict__ Tab) {
  __shared__ float kk[32];
  int tid = threadIdx.x;
  int lh = blockIdx.x;
  char* tb = Tab + (size_t)lh * TABB;
  if (tid < 32) {
    int n = tid;
    const float4 pq = reinterpret_cast<const float4*>(P)[(size_t)lh * NN2 + n];
    float wr = pq.x, wi = pq.y, c2r = pq.z, c2i = pq.w;
    int mt = n >> 4;
    float pr = 1.0f, pi = 0.0f;   // w^d
    for (int d = 0; d < 32; ++d) {
      {  // WA at t = 31-d
        int t_ = 31 - d;
        int lane = ((t_ >> 3) << 4) + (n & 15);
        int j = t_ & 7;
        unsigned short hr = bf16bits(pr);
        unsigned short lr = bf16bits(pr - bfval(hr));
        unsigned short hi_ = bf16bits(pi);
        unsigned short li_ = bf16bits(pi - bfval(hi_));
        *(unsigned short*)(tb + (mt * 2 + 0) * 1024 + lane * 16 + j * 2) = hr;
        *(unsigned short*)(tb + (mt * 2 + 1) * 1024 + lane * 16 + j * 2) = hi_;
        *(unsigned short*)(tb + 4096 + (mt * 2 + 0) * 1024 + lane * 16 + j * 2) = lr;
        *(unsigned short*)(tb + 4096 + (mt * 2 + 1) * 1024 + lane * 16 + j * 2) = li_;
      }
      {  // WC at t = d
        int mtT = d >> 4;
        int lane = (((n & 15) >> 2) << 4) + (d & 15);
        int jre = n & 3, jim = (n & 3) + 4;
        unsigned short hr = bf16bits(pr);
        unsigned short lr = bf16bits(pr - bfval(hr));
        float nim = -pi;
        unsigned short hi_ = bf16bits(nim);
        unsigned short li_ = bf16bits(nim - bfval(hi_));
        char* bh = tb + 8192 + (mtT * 2 + mt) * 1024 + lane * 16;
        char* bl = tb + 12288 + (mtT * 2 + mt) * 1024 + lane * 16;
        *(unsigned short*)(bh + jre * 2) = hr;
        *(unsigned short*)(bh + jim * 2) = hi_;
        *(unsigned short*)(bl + jre * 2) = lr;
        *(unsigned short*)(bl + jim * 2) = li_;
      }
      float kp = c2r * pr - c2i * pi;
      #pragma unroll
      for (int k = 1; k < 32; k <<= 1) kp += __shfl_xor(kp, k, 32);
      if (n == 0) kk[d] = kp;
      float nr = pr * wr - pi * wi;
      pi = pr * wi + pi * wr;
      pr = nr;
    }
    // (pr,pi) = w^32
    float w32r = pr, w32i = pi;
    float c2wr = c2r * wr - c2i * wi;
    float c2wi = c2r * wi + c2i * wr;
    int s = ((n >> 4) << 2) + (n & 3);
    int gg = (n & 15) >> 2;
    float pmr = 1.0f, pmi = 0.0f;   // w32^m
    for (int m = 0; m < 16; ++m) {
      float* q = (float*)(tb + 20480 + (size_t)((s * 64) + (gg * 16 + m)) * 24);
      q[0] = w32r; q[1] = w32i; q[2] = pmr; q[3] = pmi; q[4] = c2wr; q[5] = c2wi;
      float t2 = pmr * w32r - pmi * w32i;
      pmi = pmr * w32i + pmi * w32r;
      pmr = t2;
    }
  }
  __syncthreads();
  for (int idx = tid; idx < 1024; idx += 64) {
    int mt = idx >> 9, rem = idx & 511;
    int lane = rem >> 3, j = rem & 7;
    int tt = (mt << 4) + (lane & 15);
    int jf = ((lane >> 4) << 3) + j;
    float val = (jf <= tt) ? kk[tt - jf] : 0.0f;
    unsigned short hb = bf16bits(val);
    unsigned short lb = bf16bits(val - bfval(hb));
    *(unsigned short*)(tb + 16384 + mt * 1024 + lane * 16 + j * 2) = hb;
    *(unsigned short*)(tb + 18432 + mt * 1024 + lane * 16 + j * 2) = lb;
  }
}

// ---------------------------------------------------------------------------
// fp32 -> bf16 convert (CW weights).
// ---------------------------------------------------------------------------
__global__ __launch_bounds__(256) void k_tobf16(const float* __restrict__ src,
                                                __hip_bfloat16* __restrict__ dst,
                                                int n) {
  int i = (blockIdx.x * 256 + threadIdx.x) * 4;
  if (i >= n) return;
  float4 v = *reinterpret_cast<const float4*>(&src[i]);
  dst[i + 0] = __float2bfloat16(v.x);
  dst[i + 1] = __float2bfloat16(v.y);
  dst[i + 2] = __float2bfloat16(v.z);
  dst[i + 3] = __float2bfloat16(v.w);
}

// ---------------------------------------------------------------------------
// Input GEMM (fp32): U[b,h,l] = sum_k X[b,l,k] * W[k,h] + bias[h]
// ---------------------------------------------------------------------------
__global__ __launch_bounds__(256) void k_ingemm(const float* __restrict__ X,
                                                const float* __restrict__ W,
                                                const float* __restrict__ bias,
                                                float* __restrict__ U) {
  __shared__ float At[32][132];
  __shared__ float Bt[32][132];
  int lt = blockIdx.x * 128;
  int ht = blockIdx.y * 128;
  int b  = blockIdx.z;
  int tid = threadIdx.x;
  int tr = tid >> 4, tc = tid & 15;
  int r0 = tr * 4, c0 = tc * 4;
  float acc[2][2][4][4] = {};
  for (int kt = 0; kt < INP; kt += 32) {
    for (int i = tid; i < 32 * 128; i += 256) {
      int k = i >> 7, r = i & 127;
      At[k][r] = W[(size_t)(kt + k) * HH + ht + r];
    }
    {
      int k4 = (tid & 7) * 4;
      int cb = tid >> 3;
      #pragma unroll
      for (int p = 0; p < 4; ++p) {
        int c = cb + 32 * p;
        const float4 v = *reinterpret_cast<const float4*>(
            &X[((size_t)b * LL + lt + c) * INP + kt + k4]);
        Bt[k4 + 0][c] = v.x; Bt[k4 + 1][c] = v.y;
        Bt[k4 + 2][c] = v.z; Bt[k4 + 3][c] = v.w;
      }
    }
    __syncthreads();
    #pragma unroll
    for (int k = 0; k < 32; ++k) {
      float4 a0 = *reinterpret_cast<const float4*>(&At[k][r0]);
      float4 a1 = *reinterpret_cast<const float4*>(&At[k][r0 + 64]);
      float4 b0 = *reinterpret_cast<const float4*>(&Bt[k][c0]);
      float4 b1 = *reinterpret_cast<const float4*>(&Bt[k][c0 + 64]);
      float ar[2][4] = {{a0.x, a0.y, a0.z, a0.w}, {a1.x, a1.y, a1.z, a1.w}};
      float bc[2][4] = {{b0.x, b0.y, b0.z, b0.w}, {b1.x, b1.y, b1.z, b1.w}};
      #pragma unroll
      for (int p = 0; p < 2; ++p)
        #pragma unroll
        for (int q = 0; q < 2; ++q)
          #pragma unroll
          for (int i = 0; i < 4; ++i)
            #pragma unroll
            for (int j = 0; j < 4; ++j)
              acc[p][q][i][j] = fmaf(ar[p][i], bc[q][j], acc[p][q][i][j]);
    }
    __syncthreads();
  }
  #pragma unroll
  for (int p = 0; p < 2; ++p)
    #pragma unroll
    for (int i = 0; i < 4; ++i) {
      int h = ht + r0 + p * 64 + i;
      float bv = bias[h];
      #pragma unroll
      for (int q = 0; q < 2; ++q) {
        float4 o;
        o.x = acc[p][q][i][0] + bv;
        o.y = acc[p][q][i][1] + bv;
        o.z = acc[p][q][i][2] + bv;
        o.w = acc[p][q][i][3] + bv;
        *reinterpret_cast<float4*>(&U[((size_t)b * HH + h) * LL + lt + c0 + q * 64]) = o;
      }
    }
}

// ---------------------------------------------------------------------------
// MFMA chunk-parallel S4D scan. One wave per (b,h) row; block = 4 rows.
// T=32, 64 chunks. Phase A (chunk summaries), 32-tap FIR, phase C (carry
// expansion) on 16x16x32 bf16 MFMA with split-bf16 (hihi+hilo+lohi).
// Kogge-Stone over 16-lane segments x 4 sequential c0-tiles in fp32.
// Output bf16 Y[b][h][l] = gelu(yconv + D*u).
// ---------------------------------------------------------------------------
__global__ __launch_bounds__(256) void k_scan(const float* __restrict__ U,
                                              __hip_bfloat16* __restrict__ Ybf,
                                              const char* __restrict__ Tab,
                                              const float* __restrict__ Dp) {
  int t = threadIdx.x;
  int lane = t & 63;
  int row = __builtin_amdgcn_readfirstlane(blockIdx.x * 4 + (t >> 6));
  int h = row & (HH - 1);
  const char* tb = Tab + (size_t)h * TABB;
  const float* urow = U + (size_t)row * LL;
  int g = lane >> 4, m = lane & 15;

  // u as B-fragments (hi/lo): elem = 512*c0 + 32*m + 8*g + j
  short8 uh[4], ul[4];
  #pragma unroll
  for (int c0 = 0; c0 < 4; ++c0) {
    const float* p = urow + 512 * c0 + 32 * m + 8 * g;
    float4 va = *reinterpret_cast<const float4*>(p);
    float4 vb = *reinterpret_cast<const float4*>(p + 4);
    float v[8] = {va.x, va.y, va.z, va.w, vb.x, vb.y, vb.z, vb.w};
    short8 hi, lo;
    #pragma unroll
    for (int j = 0; j < 8; ++j) {
      unsigned short hb = bf16bits(v[j]);
      hi[j] = (short)hb;
      lo[j] = (short)bf16bits(v[j] - bfval(hb));
    }
    uh[c0] = hi;
    ul[c0] = lo;
  }

  // phase A: Z[n, c] = sum_t w_n^{31-t} u[32c+t]
  f32x4 Z[2][2][4];
  #pragma unroll
  for (int mt = 0; mt < 2; ++mt)
    #pragma unroll
    for (int reim = 0; reim < 2; ++reim) {
      short8 whi = *reinterpret_cast<const short8*>(tb + (mt * 2 + reim) * 1024 + lane * 16);
      short8 wlo = *reinterpret_cast<const short8*>(tb + 4096 + (mt * 2 + reim) * 1024 + lane * 16);
      #pragma unroll
      for (int c0 = 0; c0 < 4; ++c0) {
        f32x4 z = {0.f, 0.f, 0.f, 0.f};
        z = __builtin_amdgcn_mfma_f32_16x16x32_bf16(whi, uh[c0], z, 0, 0, 0);
        z = __builtin_amdgcn_mfma_f32_16x16x32_bf16(whi, ul[c0], z, 0, 0, 0);
        z = __builtin_amdgcn_mfma_f32_16x16x32_bf16(wlo, uh[c0], z, 0, 0, 0);
        Z[mt][reim][c0] = z;
      }
    }

  // scan over chunks (fp32): per slot s: n = 16*(s>>2) + 4*g + (s&3)
  float aR[8][4], aI[8][4];
  #pragma unroll
  for (int s = 0; s < 8; ++s) {
    int mt = s >> 2, i = s & 3;
    const char* plb = tb + 20480 + (size_t)(s * 64 + lane) * 24;
    f32x2 w32 = *reinterpret_cast<const f32x2*>(plb);
    f32x2 w32m = *reinterpret_cast<const f32x2*>(plb + 8);
    f32x2 c2w = *reinterpret_cast<const f32x2*>(plb + 16);
    float r1r = w32[0], r1i = w32[1];
    float r2r = r1r * r1r - r1i * r1i, r2i = 2.f * r1r * r1i;
    float r4r = r2r * r2r - r2i * r2i, r4i = 2.f * r2r * r2i;
    float r8r = r4r * r4r - r4i * r4i, r8i = 2.f * r4r * r4i;
    float w16r = r8r * r8r - r8i * r8i, w16i = 2.f * r8r * r8i;  // w32^16
    float Sr = 0.f, Si = 0.f;
    #pragma unroll
    for (int c0 = 0; c0 < 4; ++c0) {
      float Pr = Z[mt][0][c0][i], Pi = Z[mt][1][c0][i];
      {
        float qr = __shfl_up(Pr, 1u, 16), qi = __shfl_up(Pi, 1u, 16);
        if (m < 1) { qr = 0.f; qi = 0.f; }
        Pr = fmaf(r1r, qr, fmaf(-r1i, qi, Pr));
        Pi = fmaf(r1r, qi, fmaf(r1i, qr, Pi));
      }
      {
        float qr = __shfl_up(Pr, 2u, 16), qi = __shfl_up(Pi, 2u, 16);
        if (m < 2) { qr = 0.f; qi = 0.f; }
        Pr = fmaf(r2r, qr, fmaf(-r2i, qi, Pr));
        Pi = fmaf(r2r, qi, fmaf(r2i, qr, Pi));
      }
      {
        float qr = __shfl_up(Pr, 4u, 16), qi = __shfl_up(Pi, 4u, 16);
        if (m < 4) { qr = 0.f; qi = 0.f; }
        Pr = fmaf(r4r, qr, fmaf(-r4i, qi, Pr));
        Pi = fmaf(r4r, qi, fmaf(r4i, qr, Pi));
      }
      {
        float qr = __shfl_up(Pr, 8u, 16), qi = __shfl_up(Pi, 8u, 16);
        if (m < 8) { qr = 0.f; qi = 0.f; }
        Pr = fmaf(r8r, qr, fmaf(-r8i, qi, Pr));
        Pi = fmaf(r8r, qi, fmaf(r8i, qr, Pi));
      }
      // exclusive-with-carry: E = shfl_up(P,1)|0 + w32^m * S
      float eqr = __shfl_up(Pr, 1u, 16), eqi = __shfl_up(Pi, 1u, 16);
      if (m == 0) { eqr = 0.f; eqi = 0.f; }
      float Er = fmaf(w32m[0], Sr, fmaf(-w32m[1], Si, eqr));
      float Ei = fmaf(w32m[0], Si, fmaf(w32m[1], Sr, eqi));
      aR[s][c0] = c2w[0] * Er - c2w[1] * Ei;
      aI[s][c0] = c2w[0] * Ei + c2w[1] * Er;
      // S = w32^16 * S + P[15]
      float lr = __shfl(Pr, 15, 16), li = __shfl(Pi, 15, 16);
      float nS = fmaf(w16r, Sr, fmaf(-w16i, Si, lr));
      Si = fmaf(w16r, Si, fmaf(w16i, Sr, li));
      Sr = nS;
    }
  }

  // pack a into B-fragments (hi/lo): frag[kt][c0], j<4 -> aR, j>=4 -> aI
  short8 afh[2][4], afl[2][4];
  #pragma unroll
  for (int kt = 0; kt < 2; ++kt)
    #pragma unroll
    for (int c0 = 0; c0 < 4; ++c0) {
      float av[8] = {aR[kt * 4 + 0][c0], aR[kt * 4 + 1][c0], aR[kt * 4 + 2][c0], aR[kt * 4 + 3][c0],
                     aI[kt * 4 + 0][c0], aI[kt * 4 + 1][c0], aI[kt * 4 + 2][c0], aI[kt * 4 + 3][c0]};
      short8 hi, lo;
      #pragma unroll
      for (int j = 0; j < 8; ++j) {
        unsigned short hb = bf16bits(av[j]);
        hi[j] = (short)hb;
        lo[j] = (short)bf16bits(av[j] - bfval(hb));
      }
      afh[kt][c0] = hi;
      afl[kt][c0] = lo;
    }

  // FIR + phase C
  f32x4 y[2][4];
  #pragma unroll
  for (int mtT = 0; mtT < 2; ++mtT) {
    short8 fh = *reinterpret_cast<const short8*>(tb + 16384 + mtT * 1024 + lane * 16);
    short8 fl = *reinterpret_cast<const short8*>(tb + 18432 + mtT * 1024 + lane * 16);
    short8 wch0 = *reinterpret_cast<const short8*>(tb + 8192 + (mtT * 2 + 0) * 1024 + lane * 16);
    short8 wcl0 = *reinterpret_cast<const short8*>(tb + 12288 + (mtT * 2 + 0) * 1024 + lane * 16);
    short8 wch1 = *reinterpret_cast<const short8*>(tb + 8192 + (mtT * 2 + 1) * 1024 + lane * 16);
    short8 wcl1 = *reinterpret_cast<const short8*>(tb + 12288 + (mtT * 2 + 1) * 1024 + lane * 16);
    #pragma unroll
    for (int c0 = 0; c0 < 4; ++c0) {
      f32x4 acc = {0.f, 0.f, 0.f, 0.f};
      acc = __builtin_amdgcn_mfma_f32_16x16x32_bf16(fh, uh[c0], acc, 0, 0, 0);
      acc = __builtin_amdgcn_mfma_f32_16x16x32_bf16(fh, ul[c0], acc, 0, 0, 0);
      acc = __builtin_amdgcn_mfma_f32_16x16x32_bf16(fl, uh[c0], acc, 0, 0, 0);
      acc = __builtin_amdgcn_mfma_f32_16x16x32_bf16(wch0, afh[0][c0], acc, 0, 0, 0);
      acc = __builtin_amdgcn_mfma_f32_16x16x32_bf16(wch0, afl[0][c0], acc, 0, 0, 0);
      acc = __builtin_amdgcn_mfma_f32_16x16x32_bf16(wcl0, afh[0][c0], acc, 0, 0, 0);
      acc = __builtin_amdgcn_mfma_f32_16x16x32_bf16(wch1, afh[1][c0], acc, 0, 0, 0);
      acc = __builtin_amdgcn_mfma_f32_16x16x32_bf16(wch1, afl[1][c0], acc, 0, 0, 0);
      acc = __builtin_amdgcn_mfma_f32_16x16x32_bf16(wcl1, afh[1][c0], acc, 0, 0, 0);
      y[mtT][c0] = acc;
    }
  }

  // epilogue: + D*u (exact fp32 u), GELU, store bf16
  float Dv = Dp[h];
  #pragma unroll
  for (int mtT = 0; mtT < 2; ++mtT)
    #pragma unroll
    for (int c0 = 0; c0 < 4; ++c0) {
      int eb = 512 * c0 + 32 * m + 16 * mtT + 4 * g;
      float4 uu = *reinterpret_cast<const float4*>(urow + eb);
      f32x4 vv = y[mtT][c0];
      unsigned short b0 = bf16bits(gelu_fast(fmaf(Dv, uu.x, vv[0])));
      unsigned short b1 = bf16bits(gelu_fast(fmaf(Dv, uu.y, vv[1])));
      unsigned short b2 = bf16bits(gelu_fast(fmaf(Dv, uu.z, vv[2])));
      unsigned short b3 = bf16bits(gelu_fast(fmaf(Dv, uu.w, vv[3])));
      uint2 wo;
      wo.x = (unsigned int)b0 | ((unsigned int)b1 << 16);
      wo.y = (unsigned int)b2 | ((unsigned int)b3 << 16);
      *reinterpret_cast<uint2*>(Ybf + (size_t)row * LL + eb) = wo;
    }
}

// ---------------------------------------------------------------------------
// Transpose bf16 [b][h][l] -> [b][l][h].  Tile 32h x 128l per block.
// ---------------------------------------------------------------------------
__global__ __launch_bounds__(256) void k_transpose(const __hip_bfloat16* __restrict__ src,
                                                   __hip_bfloat16* __restrict__ dst) {
  __shared__ short lds[32][132];
  int t = threadIdx.x;
  int l0 = blockIdx.x * 128;
  int h0 = blockIdx.y * 32;
  int b  = blockIdx.z;
  const short* S = (const short*)(src + (size_t)b * HH * LL);
  short* D = (short*)(dst + (size_t)b * LL * HH);
  {
    int h = t >> 3, s0 = (t & 7) * 2;
    #pragma unroll
    for (int s = s0; s < s0 + 2; ++s) {
      float4 v = *reinterpret_cast<const float4*>(&S[(size_t)(h0 + h) * LL + l0 + s * 8]);
      *reinterpret_cast<float2*>(&lds[h][s * 8])     = make_float2(v.x, v.y);
      *reinterpret_cast<float2*>(&lds[h][s * 8 + 4]) = make_float2(v.z, v.w);
    }
  }
  __syncthreads();
  {
    int l = t >> 1, half = t & 1;
    unsigned int w[8];
    #pragma unroll
    for (int j = 0; j < 8; ++j) {
      unsigned short s0 = (unsigned short)lds[half * 16 + 2 * j][l];
      unsigned short s1 = (unsigned short)lds[half * 16 + 2 * j + 1][l];
      w[j] = (unsigned int)s0 | ((unsigned int)s1 << 16);
    }
    uint4* dp = reinterpret_cast<uint4*>(&D[(size_t)(l0 + l) * HH + h0 + half * 16]);
    dp[0] = make_uint4(w[0], w[1], w[2], w[3]);
    dp[1] = make_uint4(w[4], w[5], w[6], w[7]);
  }
}

// ---------------------------------------------------------------------------
// conv1x1 + GLU, bf16 MFMA 16x16x32.
// ---------------------------------------------------------------------------
__global__ __launch_bounds__(256) void k_conv(const __hip_bfloat16* __restrict__ Ytb,
                                              const __hip_bfloat16* __restrict__ CWb,
                                              const float* __restrict__ CB,
                                              float* __restrict__ U) {
  __shared__ short Alds[128 * 64];
  __shared__ short Blds[128 * 64];
  int lt = blockIdx.x * 128;
  int ot = blockIdx.y * 64;
  int b  = blockIdx.z;
  int t = threadIdx.x;
  int wid = t >> 6, lane = t & 63;
  int wr = wid >> 1, wc = wid & 1;
  int l15 = lane & 15, l4 = lane >> 4;
  f32x4 zero = {0.f, 0.f, 0.f, 0.f};
  f32x4 accA[2][4], accG[2][4];
  #pragma unroll
  for (int m = 0; m < 2; ++m)
    #pragma unroll
    for (int n = 0; n < 4; ++n) { accA[m][n] = zero; accG[m][n] = zero; }

  const char* Yb = (const char*)(Ytb + (size_t)b * LL * HH);
  const char* Wb = (const char*)CWb;

  for (int kt = 0; kt < HH; kt += 64) {
    #pragma unroll
    for (int it = 0; it < 4; ++it) {
      int d = 16 * (t + 256 * it);
      int rowl = d >> 7, cb = d & 127;
      int orow = (rowl < 64) ? (ot + rowl) : (448 + ot + rowl);
      gload16(Wb + (size_t)orow * 1024 + kt * 2 + (cb ^ ((rowl & 7) << 4)),
              (char*)Alds + d);
    }
    #pragma unroll
    for (int it = 0; it < 4; ++it) {
      int d = 16 * (t + 256 * it);
      int rowl = d >> 7, cb = d & 127;
      gload16(Yb + ((size_t)(lt + rowl) * 512 + kt) * 2 + (cb ^ ((rowl & 7) << 4)),
              (char*)Blds + d);
    }
    __syncthreads();
    #pragma unroll
    for (int ks = 0; ks < 2; ++ks) {
      short8 af[4], bf[4];
      #pragma unroll
      for (int m = 0; m < 4; ++m) {
        int mrow = ((m < 2) ? (wr * 32 + m * 16) : (64 + wr * 32 + (m - 2) * 16)) + l15;
        int colb = (ks * 64 + 16 * l4) ^ ((mrow & 7) << 4);
        af[m] = *reinterpret_cast<const short8*>((const char*)Alds + mrow * 128 + colb);
      }
      #pragma unroll
      for (int n = 0; n < 4; ++n) {
        int nrow = wc * 64 + n * 16 + l15;
        int colb = (ks * 64 + 16 * l4) ^ ((nrow & 7) << 4);
        bf[n] = *reinterpret_cast<const short8*>((const char*)Blds + nrow * 128 + colb);
      }
      #pragma unroll
      for (int m = 0; m < 2; ++m)
        #pragma unroll
        for (int n = 0; n < 4; ++n) {
          accA[m][n] = __builtin_amdgcn_mfma_f32_16x16x32_bf16(af[m], bf[n], accA[m][n], 0, 0, 0);
          accG[m][n] = __builtin_amdgcn_mfma_f32_16x16x32_bf16(af[m + 2], bf[n], accG[m][n], 0, 0, 0);
        }
    }
    __syncthreads();
  }
  #pragma unroll
  for (int m = 0; m < 2; ++m) {
    #pragma unroll
    for (int r = 0; r < 4; ++r) {
      int rowl = wr * 32 + m * 16 + l4 * 4 + r;
      float ba = CB[ot + rowl];
      float bg = CB[512 + ot + rowl];
      float* urow_ = U + ((size_t)b * HH + ot + rowl) * LL + lt + wc * 64;
      #pragma unroll
      for (int n = 0; n < 4; ++n) {
        float a = accA[m][n][r] + ba;
        float g = accG[m][n][r] + bg;
        urow_[n * 16 + l15] = a * sigmoidf_(g);
      }
    }
  }
}

// ---------------------------------------------------------------------------
// Output projection (fp32 out).
// ---------------------------------------------------------------------------
__global__ __launch_bounds__(256) void k_outgemm(const float* __restrict__ U,
                                                 const float* __restrict__ Wo,
                                                 const float* __restrict__ bo,
                                                 float* __restrict__ out) {
  int bl = blockIdx.x * 256 + threadIdx.x;
  int b = bl >> 11, l = bl & (LL - 1);
  float a0 = 0.0f, a1 = 0.0f;
  const float* up = U + (size_t)b * HH * LL + l;
  #pragma unroll 4
  for (int h = 0; h < HH; ++h) {
    float v = up[(size_t)h * LL];
    a0 = fmaf(v, Wo[h * 2 + 0], a0);
    a1 = fmaf(v, Wo[h * 2 + 1], a1);
  }
  out[(size_t)bl * 2 + 0] = a0 + bo[0];
  out[(size_t)bl * 2 + 1] = a1 + bo[1];
}

extern "C" void kernel_launch(void* const* d_in, const int* in_sizes, int n_in,
                              void* d_out, int out_size, void* d_ws, size_t ws_size,
                              hipStream_t stream) {
  const float* X      = (const float*)d_in[0];
  const float* Win    = (const float*)d_in[1];
  const float* bin    = (const float*)d_in[2];
  const float* log_dt = (const float*)d_in[3];
  const float* Cri    = (const float*)d_in[4];
  const float* lAr    = (const float*)d_in[5];
  const float* Aim    = (const float*)d_in[6];
  const float* Dp     = (const float*)d_in[7];
  const float* CW     = (const float*)d_in[8];
  const float* CB     = (const float*)d_in[9];
  const float* Wo     = (const float*)d_in[10];
  const float* bo     = (const float*)d_in[11];
  float* out = (float*)d_out;

  const size_t Pfloats   = (size_t)NNL * HH * NN2 * 4;        // 262144
  const size_t CWfloats  = (size_t)NNL * 2 * HH * HH / 2;     // 1048576
  const size_t Tabfloats = (size_t)NNL * HH * (TABB / 4);     // 16777216
  const size_t HL        = (size_t)HH * LL;                   // 1048576

  float* P = (float*)d_ws;
  __hip_bfloat16* CWb = (__hip_bfloat16*)(P + Pfloats);
  char* Tab = (char*)(P + Pfloats + CWfloats);
  size_t head = Pfloats + CWfloats + Tabfloats;

  size_t ws_floats = ws_size / sizeof(float);
  size_t avail = (ws_floats > head) ? (ws_floats - head) : 0;
  int G = (int)(avail / (HL + HL / 2));   // U fp32 + Ybf/Yt bf16
  if (G > 16) G = 16;
  if (G < 1) G = 1;

  float* U = P + head;
  __hip_bfloat16* Ybf = (__hip_bfloat16*)(U + (size_t)G * HL);
  __hip_bfloat16* Yt  = Ybf + (size_t)G * HL;

  k_params<<<(NNL * HH * NN2 + 255) / 256, 256, 0, stream>>>(log_dt, Cri, lAr, Aim, P);
  k_tables<<<NNL * HH, 64, 0, stream>>>(P, Tab);
  k_tobf16<<<(NNL * 2 * HH * HH) / 1024, 256, 0, stream>>>(CW, CWb, NNL * 2 * HH * HH);

  for (int b0 = 0; b0 < BB; b0 += G) {
    int g = (BB - b0 < G) ? (BB - b0) : G;
    k_ingemm<<<dim3(LL / 128, HH / 128, g), 256, 0, stream>>>(
        X + (size_t)b0 * LL * INP, Win, bin, U);
    for (int layer = 0; layer < NNL; ++layer) {
      k_scan<<<g * (HH / 4), 256, 0, stream>>>(
          U, Ybf,
          Tab + (size_t)layer * HH * TABB,
          Dp + (size_t)layer * HH);
      k_transpose<<<dim3(LL / 128, HH / 32, g), 256, 0, stream>>>(Ybf, Yt);
      k_conv<<<dim3(LL / 128, HH / 64, g), 256, 0, stream>>>(
          Yt, CWb + (size_t)layer * 2 * HH * HH, CB + (size_t)layer * 2 * HH, U);
    }
    k_outgemm<<<g * LL / 256, 256, 0, stream>>>(
        U, Wo, bo, out + (size_t)b0 * LL * OUTC);
  }
}

// Round 8
// 1289.578 us; speedup vs baseline: 5.8254x; 1.0273x over previous
//
#include <hip/hip_runtime.h>
#include <hip/hip_bf16.h>
#include <math.h>

#define BB 32
#define LL 2048
#define INP 192
#define OUTC 2
#define HH 512
#define NN2 32
#define NNL 4
#define TABB 32768   // bytes of table per (layer,h)

using short8 = __attribute__((ext_vector_type(8))) short;
using f32x4  = __attribute__((ext_vector_type(4))) float;
using f32x2  = __attribute__((ext_vector_type(2))) float;

__device__ __forceinline__ float sigmoidf_(float x) {
  return 1.0f / (1.0f + expf(-x));
}
__device__ __forceinline__ unsigned short bf16bits(float x) {
  __hip_bfloat16 b = __float2bfloat16(x);
  return __builtin_bit_cast(unsigned short, b);
}
__device__ __forceinline__ float bfval(unsigned short b) {
  unsigned int u = (unsigned int)b << 16;
  return __builtin_bit_cast(float, u);
}
// Abramowitz-Stegun 7.1.26 erf (max err 1.5e-7) based exact-GELU
__device__ __forceinline__ float gelu_fast(float x) {
  float s = x * 0.70710678118654752f;
  float ax = fabsf(s);
  float tt = 1.0f / fmaf(0.3275911f, ax, 1.0f);
  float p = fmaf(1.061405429f, tt, -1.453152027f);
  p = fmaf(p, tt, 1.421413741f);
  p = fmaf(p, tt, -0.284496736f);
  p = fmaf(p, tt, 0.254829592f);
  float e = __expf(-s * s);
  float er = 1.0f - p * tt * e;
  er = copysignf(er, s);
  return 0.5f * x * (1.0f + er);
}
__device__ __forceinline__ void gload16(const void* gsrc, void* ldst) {
  __builtin_amdgcn_global_load_lds(
      (const __attribute__((address_space(1))) void*)gsrc,
      (__attribute__((address_space(3))) void*)ldst, 16, 0, 0);
}

// ---------------------------------------------------------------------------
// P[NL][H][N2][4] = {w_re, w_im, c2_re, c2_im}
// ---------------------------------------------------------------------------
__global__ __launch_bounds__(256) void k_params(const float* __restrict__ log_dt,
                                                const float* __restrict__ Cri,
                                                const float* __restrict__ lAr,
                                                const float* __restrict__ Aim,
                                                float* __restrict__ P) {
  int idx = blockIdx.x * 256 + threadIdx.x;
  if (idx >= NNL * HH * NN2) return;
  float dt  = expf(log_dt[idx / NN2]);
  float Are = -expf(lAr[idx]);
  float Aimv = Aim[idx];
  float dre = Are * dt, dim = Aimv * dt;
  float er = expf(dre);
  float wrv = er * cosf(dim);
  float wiv = er * sinf(dim);
  float Er = wrv - 1.0f, Ei = wiv;
  float den = Are * Are + Aimv * Aimv;
  float Fr = (Er * Are + Ei * Aimv) / den;
  float Fi = (Ei * Are - Er * Aimv) / den;
  float Cre = Cri[idx * 2 + 0], Cim = Cri[idx * 2 + 1];
  P[idx * 4 + 0] = wrv;
  P[idx * 4 + 1] = wiv;
  P[idx * 4 + 2] = 2.0f * (Cre * Fr - Cim * Fi);
  P[idx * 4 + 3] = 2.0f * (Cre * Fi + Cim * Fr);
}

// ---------------------------------------------------------------------------
// Build per-(layer,h) MFMA fragment tables (split bf16 hi/lo) + scan tables.
// (unchanged from round 7; see comments there)
// ---------------------------------------------------------------------------
__global__ __launch_bounds__(64) void k_tables(const float* __restrict__ P,
                                               char* __restrict__ Tab) {
  __shared__ float kk[32];
  int tid = threadIdx.x;
  int lh = blockIdx.x;
  char* tb = Tab + (size_t)lh * TABB;
  if (tid < 32) {
    int n = tid;
    const float4 pq = reinterpret_cast<const float4*>(P)[(size_t)lh * NN2 + n];
    float wr = pq.x, wi = pq.y, c2r = pq.z, c2i = pq.w;
    int mt = n >> 4;
    float pr = 1.0f, pi = 0.0f;   // w^d
    for (int d = 0; d < 32; ++d) {
      {  // WA at t = 31-d
        int t_ = 31 - d;
        int lane = ((t_ >> 3) << 4) + (n & 15);
        int j = t_ & 7;
        unsigned short hr = bf16bits(pr);
        unsigned short lr = bf16bits(pr - bfval(hr));
        unsigned short hi_ = bf16bits(pi);
        unsigned short li_ = bf16bits(pi - bfval(hi_));
        *(unsigned short*)(tb + (mt * 2 + 0) * 1024 + lane * 16 + j * 2) = hr;
        *(unsigned short*)(tb + (mt * 2 + 1) * 1024 + lane * 16 + j * 2) = hi_;
        *(unsigned short*)(tb + 4096 + (mt * 2 + 0) * 1024 + lane * 16 + j * 2) = lr;
        *(unsigned short*)(tb + 4096 + (mt * 2 + 1) * 1024 + lane * 16 + j * 2) = li_;
      }
      {  // WC at t = d
        int mtT = d >> 4;
        int lane = (((n & 15) >> 2) << 4) + (d & 15);
        int jre = n & 3, jim = (n & 3) + 4;
        unsigned short hr = bf16bits(pr);
        unsigned short lr = bf16bits(pr - bfval(hr));
        float nim = -pi;
        unsigned short hi_ = bf16bits(nim);
        unsigned short li_ = bf16bits(nim - bfval(hi_));
        char* bh = tb + 8192 + (mtT * 2 + mt) * 1024 + lane * 16;
        char* bl = tb + 12288 + (mtT * 2 + mt) * 1024 + lane * 16;
        *(unsigned short*)(bh + jre * 2) = hr;
        *(unsigned short*)(bh + jim * 2) = hi_;
        *(unsigned short*)(bl + jre * 2) = lr;
        *(unsigned short*)(bl + jim * 2) = li_;
      }
      float kp = c2r * pr - c2i * pi;
      #pragma unroll
      for (int k = 1; k < 32; k <<= 1) kp += __shfl_xor(kp, k, 32);
      if (n == 0) kk[d] = kp;
      float nr = pr * wr - pi * wi;
      pi = pr * wi + pi * wr;
      pr = nr;
    }
    float w32r = pr, w32i = pi;
    float c2wr = c2r * wr - c2i * wi;
    float c2wi = c2r * wi + c2i * wr;
    int s = ((n >> 4) << 2) + (n & 3);
    int gg = (n & 15) >> 2;
    float pmr = 1.0f, pmi = 0.0f;   // w32^m
    for (int m = 0; m < 16; ++m) {
      float* q = (float*)(tb + 20480 + (size_t)((s * 64) + (gg * 16 + m)) * 24);
      q[0] = w32r; q[1] = w32i; q[2] = pmr; q[3] = pmi; q[4] = c2wr; q[5] = c2wi;
      float t2 = pmr * w32r - pmi * w32i;
      pmi = pmr * w32i + pmi * w32r;
      pmr = t2;
    }
  }
  __syncthreads();
  for (int idx = tid; idx < 1024; idx += 64) {
    int mt = idx >> 9, rem = idx & 511;
    int lane = rem >> 3, j = rem & 7;
    int tt = (mt << 4) + (lane & 15);
    int jf = ((lane >> 4) << 3) + j;
    float val = (jf <= tt) ? kk[tt - jf] : 0.0f;
    unsigned short hb = bf16bits(val);
    unsigned short lb = bf16bits(val - bfval(hb));
    *(unsigned short*)(tb + 16384 + mt * 1024 + lane * 16 + j * 2) = hb;
    *(unsigned short*)(tb + 18432 + mt * 1024 + lane * 16 + j * 2) = lb;
  }
}

// ---------------------------------------------------------------------------
// fp32 -> bf16 convert (CW weights).
// ---------------------------------------------------------------------------
__global__ __launch_bounds__(256) void k_tobf16(const float* __restrict__ src,
                                                __hip_bfloat16* __restrict__ dst,
                                                int n) {
  int i = (blockIdx.x * 256 + threadIdx.x) * 4;
  if (i >= n) return;
  float4 v = *reinterpret_cast<const float4*>(&src[i]);
  dst[i + 0] = __float2bfloat16(v.x);
  dst[i + 1] = __float2bfloat16(v.y);
  dst[i + 2] = __float2bfloat16(v.z);
  dst[i + 3] = __float2bfloat16(v.w);
}

// ---------------------------------------------------------------------------
// Split X fp32 -> Xhi/Xlo bf16 planes (same [b][l][k] layout).
// ---------------------------------------------------------------------------
__global__ __launch_bounds__(256) void k_splitx(const float* __restrict__ src,
                                                __hip_bfloat16* __restrict__ hi,
                                                __hip_bfloat16* __restrict__ lo,
                                                int n) {
  int i = (blockIdx.x * 256 + threadIdx.x) * 4;
  if (i >= n) return;
  float4 v = *reinterpret_cast<const float4*>(&src[i]);
  float vv[4] = {v.x, v.y, v.z, v.w};
  unsigned short hb[4], lb[4];
  #pragma unroll
  for (int j = 0; j < 4; ++j) {
    hb[j] = bf16bits(vv[j]);
    lb[j] = bf16bits(vv[j] - bfval(hb[j]));
  }
  *reinterpret_cast<uint2*>(hi + i) = make_uint2(
      (unsigned)hb[0] | ((unsigned)hb[1] << 16), (unsigned)hb[2] | ((unsigned)hb[3] << 16));
  *reinterpret_cast<uint2*>(lo + i) = make_uint2(
      (unsigned)lb[0] | ((unsigned)lb[1] << 16), (unsigned)lb[2] | ((unsigned)lb[3] << 16));
}

// ---------------------------------------------------------------------------
// W[k][h] fp32 -> Wt hi/lo bf16 [h][k] (transposed, split). One-time, tiny.
// ---------------------------------------------------------------------------
__global__ __launch_bounds__(256) void k_prepwt(const float* __restrict__ W,
                                                __hip_bfloat16* __restrict__ hi,
                                                __hip_bfloat16* __restrict__ lo) {
  int idx = blockIdx.x * 256 + threadIdx.x;   // h*INP + k
  if (idx >= HH * INP) return;
  int h = idx / INP, k = idx - h * INP;
  float v = W[(size_t)k * HH + h];
  unsigned short hb = bf16bits(v);
  hi[idx] = __builtin_bit_cast(__hip_bfloat16, hb);
  lo[idx] = __float2bfloat16(v - bfval(hb));
}

// ---------------------------------------------------------------------------
// Input GEMM, bf16 MFMA split (hi*hi+hi*lo+lo*hi ~ fp32).
// U[b,h,l] = sum_k X[b,l,k] W[k,h] + bias[h].
// A = Xsplit[l][k] (M=l), B = Wt[h][k] (N=h); D: col=lane&15 -> h,
// row=(lane>>4)*4+r -> l (16B-contiguous stores in U[h][l]).
// No LDS; X/Wt rows read directly (Wt is L2-resident, X k-contig).
// Block 256 = 4 waves in 2x2 (wave tile 64l x 64h); grid (L/128, H/128, g).
// ---------------------------------------------------------------------------
__global__ __launch_bounds__(256) void k_ingemm(const __hip_bfloat16* __restrict__ Xhi,
                                                const __hip_bfloat16* __restrict__ Xlo,
                                                const __hip_bfloat16* __restrict__ Wthi,
                                                const __hip_bfloat16* __restrict__ Wtlo,
                                                const float* __restrict__ bias,
                                                float* __restrict__ U) {
  int lt = blockIdx.x * 128;
  int ht = blockIdx.y * 128;
  int b  = blockIdx.z;
  int t = threadIdx.x;
  int wid = t >> 6, lane = t & 63;
  int wrow = wid >> 1, wcol = wid & 1;
  int l15 = lane & 15, g = lane >> 4;

  const short* Xh = (const short*)Xhi + (size_t)b * LL * INP;
  const short* Xl = (const short*)Xlo + (size_t)b * LL * INP;
  const short* Bh = (const short*)Wthi;
  const short* Bl = (const short*)Wtlo;

  f32x4 acc[4][4];
  #pragma unroll
  for (int m = 0; m < 4; ++m)
    #pragma unroll
    for (int n = 0; n < 4; ++n) acc[m][n] = f32x4{0.f, 0.f, 0.f, 0.f};

  int lbase = lt + wrow * 64 + l15;
  int hbase = ht + wcol * 64 + l15;

  #pragma unroll
  for (int ks = 0; ks < 6; ++ks) {
    int k0 = ks * 32 + 8 * g;
    short8 ah[4], al[4], bh[4], bl[4];
    #pragma unroll
    for (int m = 0; m < 4; ++m) {
      size_t off = (size_t)(lbase + m * 16) * INP + k0;
      ah[m] = *reinterpret_cast<const short8*>(Xh + off);
      al[m] = *reinterpret_cast<const short8*>(Xl + off);
    }
    #pragma unroll
    for (int n = 0; n < 4; ++n) {
      size_t off = (size_t)(hbase + n * 16) * INP + k0;
      bh[n] = *reinterpret_cast<const short8*>(Bh + off);
      bl[n] = *reinterpret_cast<const short8*>(Bl + off);
    }
    #pragma unroll
    for (int m = 0; m < 4; ++m)
      #pragma unroll
      for (int n = 0; n < 4; ++n) {
        acc[m][n] = __builtin_amdgcn_mfma_f32_16x16x32_bf16(ah[m], bh[n], acc[m][n], 0, 0, 0);
        acc[m][n] = __builtin_amdgcn_mfma_f32_16x16x32_bf16(ah[m], bl[n], acc[m][n], 0, 0, 0);
        acc[m][n] = __builtin_amdgcn_mfma_f32_16x16x32_bf16(al[m], bh[n], acc[m][n], 0, 0, 0);
      }
  }

  #pragma unroll
  for (int n = 0; n < 4; ++n) {
    int h = hbase + n * 16;
    float bv = bias[h];
    #pragma unroll
    for (int m = 0; m < 4; ++m) {
      int l0 = lt + wrow * 64 + m * 16 + g * 4;
      float4 o;
      o.x = acc[m][n][0] + bv;
      o.y = acc[m][n][1] + bv;
      o.z = acc[m][n][2] + bv;
      o.w = acc[m][n][3] + bv;
      *reinterpret_cast<float4*>(&U[((size_t)b * HH + h) * LL + l0]) = o;
    }
  }
}

// ---------------------------------------------------------------------------
// MFMA chunk-parallel S4D scan (unchanged from round 7).
// ---------------------------------------------------------------------------
__global__ __launch_bounds__(256) void k_scan(const float* __restrict__ U,
                                              __hip_bfloat16* __restrict__ Ybf,
                                              const char* __restrict__ Tab,
                                              const float* __restrict__ Dp) {
  int t = threadIdx.x;
  int lane = t & 63;
  int row = __builtin_amdgcn_readfirstlane(blockIdx.x * 4 + (t >> 6));
  int h = row & (HH - 1);
  const char* tb = Tab + (size_t)h * TABB;
  const float* urow = U + (size_t)row * LL;
  int g = lane >> 4, m = lane & 15;

  short8 uh[4], ul[4];
  #pragma unroll
  for (int c0 = 0; c0 < 4; ++c0) {
    const float* p = urow + 512 * c0 + 32 * m + 8 * g;
    float4 va = *reinterpret_cast<const float4*>(p);
    float4 vb = *reinterpret_cast<const float4*>(p + 4);
    float v[8] = {va.x, va.y, va.z, va.w, vb.x, vb.y, vb.z, vb.w};
    short8 hi, lo;
    #pragma unroll
    for (int j = 0; j < 8; ++j) {
      unsigned short hb = bf16bits(v[j]);
      hi[j] = (short)hb;
      lo[j] = (short)bf16bits(v[j] - bfval(hb));
    }
    uh[c0] = hi;
    ul[c0] = lo;
  }

  f32x4 Z[2][2][4];
  #pragma unroll
  for (int mt = 0; mt < 2; ++mt)
    #pragma unroll
    for (int reim = 0; reim < 2; ++reim) {
      short8 whi = *reinterpret_cast<const short8*>(tb + (mt * 2 + reim) * 1024 + lane * 16);
      short8 wlo = *reinterpret_cast<const short8*>(tb + 4096 + (mt * 2 + reim) * 1024 + lane * 16);
      #pragma unroll
      for (int c0 = 0; c0 < 4; ++c0) {
        f32x4 z = {0.f, 0.f, 0.f, 0.f};
        z = __builtin_amdgcn_mfma_f32_16x16x32_bf16(whi, uh[c0], z, 0, 0, 0);
        z = __builtin_amdgcn_mfma_f32_16x16x32_bf16(whi, ul[c0], z, 0, 0, 0);
        z = __builtin_amdgcn_mfma_f32_16x16x32_bf16(wlo, uh[c0], z, 0, 0, 0);
        Z[mt][reim][c0] = z;
      }
    }

  float aR[8][4], aI[8][4];
  #pragma unroll
  for (int s = 0; s < 8; ++s) {
    int mt = s >> 2, i = s & 3;
    const char* plb = tb + 20480 + (size_t)(s * 64 + lane) * 24;
    f32x2 w32 = *reinterpret_cast<const f32x2*>(plb);
    f32x2 w32m = *reinterpret_cast<const f32x2*>(plb + 8);
    f32x2 c2w = *reinterpret_cast<const f32x2*>(plb + 16);
    float r1r = w32[0], r1i = w32[1];
    float r2r = r1r * r1r - r1i * r1i, r2i = 2.f * r1r * r1i;
    float r4r = r2r * r2r - r2i * r2i, r4i = 2.f * r2r * r2i;
    float r8r = r4r * r4r - r4i * r4i, r8i = 2.f * r4r * r4i;
    float w16r = r8r * r8r - r8i * r8i, w16i = 2.f * r8r * r8i;
    float Sr = 0.f, Si = 0.f;
    #pragma unroll
    for (int c0 = 0; c0 < 4; ++c0) {
      float Pr = Z[mt][0][c0][i], Pi = Z[mt][1][c0][i];
      {
        float qr = __shfl_up(Pr, 1u, 16), qi = __shfl_up(Pi, 1u, 16);
        if (m < 1) { qr = 0.f; qi = 0.f; }
        Pr = fmaf(r1r, qr, fmaf(-r1i, qi, Pr));
        Pi = fmaf(r1r, qi, fmaf(r1i, qr, Pi));
      }
      {
        float qr = __shfl_up(Pr, 2u, 16), qi = __shfl_up(Pi, 2u, 16);
        if (m < 2) { qr = 0.f; qi = 0.f; }
        Pr = fmaf(r2r, qr, fmaf(-r2i, qi, Pr));
        Pi = fmaf(r2r, qi, fmaf(r2i, qr, Pi));
      }
      {
        float qr = __shfl_up(Pr, 4u, 16), qi = __shfl_up(Pi, 4u, 16);
        if (m < 4) { qr = 0.f; qi = 0.f; }
        Pr = fmaf(r4r, qr, fmaf(-r4i, qi, Pr));
        Pi = fmaf(r4r, qi, fmaf(r4i, qr, Pi));
      }
      {
        float qr = __shfl_up(Pr, 8u, 16), qi = __shfl_up(Pi, 8u, 16);
        if (m < 8) { qr = 0.f; qi = 0.f; }
        Pr = fmaf(r8r, qr, fmaf(-r8i, qi, Pr));
        Pi = fmaf(r8r, qi, fmaf(r8i, qr, Pi));
      }
      float eqr = __shfl_up(Pr, 1u, 16), eqi = __shfl_up(Pi, 1u, 16);
      if (m == 0) { eqr = 0.f; eqi = 0.f; }
      float Er = fmaf(w32m[0], Sr, fmaf(-w32m[1], Si, eqr));
      float Ei = fmaf(w32m[0], Si, fmaf(w32m[1], Sr, eqi));
      aR[s][c0] = c2w[0] * Er - c2w[1] * Ei;
      aI[s][c0] = c2w[0] * Ei + c2w[1] * Er;
      float lr = __shfl(Pr, 15, 16), li = __shfl(Pi, 15, 16);
      float nS = fmaf(w16r, Sr, fmaf(-w16i, Si, lr));
      Si = fmaf(w16r, Si, fmaf(w16i, Sr, li));
      Sr = nS;
    }
  }

  short8 afh[2][4], afl[2][4];
  #pragma unroll
  for (int kt = 0; kt < 2; ++kt)
    #pragma unroll
    for (int c0 = 0; c0 < 4; ++c0) {
      float av[8] = {aR[kt * 4 + 0][c0], aR[kt * 4 + 1][c0], aR[kt * 4 + 2][c0], aR[kt * 4 + 3][c0],
                     aI[kt * 4 + 0][c0], aI[kt * 4 + 1][c0], aI[kt * 4 + 2][c0], aI[kt * 4 + 3][c0]};
      short8 hi, lo;
      #pragma unroll
      for (int j = 0; j < 8; ++j) {
        unsigned short hb = bf16bits(av[j]);
        hi[j] = (short)hb;
        lo[j] = (short)bf16bits(av[j] - bfval(hb));
      }
      afh[kt][c0] = hi;
      afl[kt][c0] = lo;
    }

  f32x4 y[2][4];
  #pragma unroll
  for (int mtT = 0; mtT < 2; ++mtT) {
    short8 fh = *reinterpret_cast<const short8*>(tb + 16384 + mtT * 1024 + lane * 16);
    short8 fl = *reinterpret_cast<const short8*>(tb + 18432 + mtT * 1024 + lane * 16);
    short8 wch0 = *reinterpret_cast<const short8*>(tb + 8192 + (mtT * 2 + 0) * 1024 + lane * 16);
    short8 wcl0 = *reinterpret_cast<const short8*>(tb + 12288 + (mtT * 2 + 0) * 1024 + lane * 16);
    short8 wch1 = *reinterpret_cast<const short8*>(tb + 8192 + (mtT * 2 + 1) * 1024 + lane * 16);
    short8 wcl1 = *reinterpret_cast<const short8*>(tb + 12288 + (mtT * 2 + 1) * 1024 + lane * 16);
    #pragma unroll
    for (int c0 = 0; c0 < 4; ++c0) {
      f32x4 acc = {0.f, 0.f, 0.f, 0.f};
      acc = __builtin_amdgcn_mfma_f32_16x16x32_bf16(fh, uh[c0], acc, 0, 0, 0);
      acc = __builtin_amdgcn_mfma_f32_16x16x32_bf16(fh, ul[c0], acc, 0, 0, 0);
      acc = __builtin_amdgcn_mfma_f32_16x16x32_bf16(fl, uh[c0], acc, 0, 0, 0);
      acc = __builtin_amdgcn_mfma_f32_16x16x32_bf16(wch0, afh[0][c0], acc, 0, 0, 0);
      acc = __builtin_amdgcn_mfma_f32_16x16x32_bf16(wch0, afl[0][c0], acc, 0, 0, 0);
      acc = __builtin_amdgcn_mfma_f32_16x16x32_bf16(wcl0, afh[0][c0], acc, 0, 0, 0);
      acc = __builtin_amdgcn_mfma_f32_16x16x32_bf16(wch1, afh[1][c0], acc, 0, 0, 0);
      acc = __builtin_amdgcn_mfma_f32_16x16x32_bf16(wch1, afl[1][c0], acc, 0, 0, 0);
      acc = __builtin_amdgcn_mfma_f32_16x16x32_bf16(wcl1, afh[1][c0], acc, 0, 0, 0);
      y[mtT][c0] = acc;
    }
  }

  float Dv = Dp[h];
  #pragma unroll
  for (int mtT = 0; mtT < 2; ++mtT)
    #pragma unroll
    for (int c0 = 0; c0 < 4; ++c0) {
      int eb = 512 * c0 + 32 * m + 16 * mtT + 4 * g;
      float4 uu = *reinterpret_cast<const float4*>(urow + eb);
      f32x4 vv = y[mtT][c0];
      unsigned short b0 = bf16bits(gelu_fast(fmaf(Dv, uu.x, vv[0])));
      unsigned short b1 = bf16bits(gelu_fast(fmaf(Dv, uu.y, vv[1])));
      unsigned short b2 = bf16bits(gelu_fast(fmaf(Dv, uu.z, vv[2])));
      unsigned short b3 = bf16bits(gelu_fast(fmaf(Dv, uu.w, vv[3])));
      uint2 wo;
      wo.x = (unsigned int)b0 | ((unsigned int)b1 << 16);
      wo.y = (unsigned int)b2 | ((unsigned int)b3 << 16);
      *reinterpret_cast<uint2*>(Ybf + (size_t)row * LL + eb) = wo;
    }
}

// ---------------------------------------------------------------------------
// Transpose bf16 [b][h][l] -> [b][l][h].  Tile 32h x 128l per block.
// ---------------------------------------------------------------------------
__global__ __launch_bounds__(256) void k_transpose(const __hip_bfloat16* __restrict__ src,
                                                   __hip_bfloat16* __restrict__ dst) {
  __shared__ short lds[32][132];
  int t = threadIdx.x;
  int l0 = blockIdx.x * 128;
  int h0 = blockIdx.y * 32;
  int b  = blockIdx.z;
  const short* S = (const short*)(src + (size_t)b * HH * LL);
  short* D = (short*)(dst + (size_t)b * LL * HH);
  {
    int h = t >> 3, s0 = (t & 7) * 2;
    #pragma unroll
    for (int s = s0; s < s0 + 2; ++s) {
      float4 v = *reinterpret_cast<const float4*>(&S[(size_t)(h0 + h) * LL + l0 + s * 8]);
      *reinterpret_cast<float2*>(&lds[h][s * 8])     = make_float2(v.x, v.y);
      *reinterpret_cast<float2*>(&lds[h][s * 8 + 4]) = make_float2(v.z, v.w);
    }
  }
  __syncthreads();
  {
    int l = t >> 1, half = t & 1;
    unsigned int w[8];
    #pragma unroll
    for (int j = 0; j < 8; ++j) {
      unsigned short s0 = (unsigned short)lds[half * 16 + 2 * j][l];
      unsigned short s1 = (unsigned short)lds[half * 16 + 2 * j + 1][l];
      w[j] = (unsigned int)s0 | ((unsigned int)s1 << 16);
    }
    uint4* dp = reinterpret_cast<uint4*>(&D[(size_t)(l0 + l) * HH + h0 + half * 16]);
    dp[0] = make_uint4(w[0], w[1], w[2], w[3]);
    dp[1] = make_uint4(w[4], w[5], w[6], w[7]);
  }
}

// ---------------------------------------------------------------------------
// conv1x1 + GLU, bf16 MFMA 16x16x32.
// ---------------------------------------------------------------------------
__global__ __launch_bounds__(256) void k_conv(const __hip_bfloat16* __restrict__ Ytb,
                                              const __hip_bfloat16* __restrict__ CWb,
                                              const float* __restrict__ CB,
                                              float* __restrict__ U) {
  __shared__ short Alds[128 * 64];
  __shared__ short Blds[128 * 64];
  int lt = blockIdx.x * 128;
  int ot = blockIdx.y * 64;
  int b  = blockIdx.z;
  int t = threadIdx.x;
  int wid = t >> 6, lane = t & 63;
  int wr = wid >> 1, wc = wid & 1;
  int l15 = lane & 15, l4 = lane >> 4;
  f32x4 zero = {0.f, 0.f, 0.f, 0.f};
  f32x4 accA[2][4], accG[2][4];
  #pragma unroll
  for (int m = 0; m < 2; ++m)
    #pragma unroll
    for (int n = 0; n < 4; ++n) { accA[m][n] = zero; accG[m][n] = zero; }

  const char* Yb = (const char*)(Ytb + (size_t)b * LL * HH);
  const char* Wb = (const char*)CWb;

  for (int kt = 0; kt < HH; kt += 64) {
    #pragma unroll
    for (int it = 0; it < 4; ++it) {
      int d = 16 * (t + 256 * it);
      int rowl = d >> 7, cb = d & 127;
      int orow = (rowl < 64) ? (ot + rowl) : (448 + ot + rowl);
      gload16(Wb + (size_t)orow * 1024 + kt * 2 + (cb ^ ((rowl & 7) << 4)),
              (char*)Alds + d);
    }
    #pragma unroll
    for (int it = 0; it < 4; ++it) {
      int d = 16 * (t + 256 * it);
      int rowl = d >> 7, cb = d & 127;
      gload16(Yb + ((size_t)(lt + rowl) * 512 + kt) * 2 + (cb ^ ((rowl & 7) << 4)),
              (char*)Blds + d);
    }
    __syncthreads();
    #pragma unroll
    for (int ks = 0; ks < 2; ++ks) {
      short8 af[4], bf[4];
      #pragma unroll
      for (int m = 0; m < 4; ++m) {
        int mrow = ((m < 2) ? (wr * 32 + m * 16) : (64 + wr * 32 + (m - 2) * 16)) + l15;
        int colb = (ks * 64 + 16 * l4) ^ ((mrow & 7) << 4);
        af[m] = *reinterpret_cast<const short8*>((const char*)Alds + mrow * 128 + colb);
      }
      #pragma unroll
      for (int n = 0; n < 4; ++n) {
        int nrow = wc * 64 + n * 16 + l15;
        int colb = (ks * 64 + 16 * l4) ^ ((nrow & 7) << 4);
        bf[n] = *reinterpret_cast<const short8*>((const char*)Blds + nrow * 128 + colb);
      }
      #pragma unroll
      for (int m = 0; m < 2; ++m)
        #pragma unroll
        for (int n = 0; n < 4; ++n) {
          accA[m][n] = __builtin_amdgcn_mfma_f32_16x16x32_bf16(af[m], bf[n], accA[m][n], 0, 0, 0);
          accG[m][n] = __builtin_amdgcn_mfma_f32_16x16x32_bf16(af[m + 2], bf[n], accG[m][n], 0, 0, 0);
        }
    }
    __syncthreads();
  }
  #pragma unroll
  for (int m = 0; m < 2; ++m) {
    #pragma unroll
    for (int r = 0; r < 4; ++r) {
      int rowl = wr * 32 + m * 16 + l4 * 4 + r;
      float ba = CB[ot + rowl];
      float bg = CB[512 + ot + rowl];
      float* urow_ = U + ((size_t)b * HH + ot + rowl) * LL + lt + wc * 64;
      #pragma unroll
      for (int n = 0; n < 4; ++n) {
        float a = accA[m][n][r] + ba;
        float g = accG[m][n][r] + bg;
        urow_[n * 16 + l15] = a * sigmoidf_(g);
      }
    }
  }
}

// ---------------------------------------------------------------------------
// Output projection (fp32 out).
// ---------------------------------------------------------------------------
__global__ __launch_bounds__(256) void k_outgemm(const float* __restrict__ U,
                                                 const float* __restrict__ Wo,
                                                 const float* __restrict__ bo,
                                                 float* __restrict__ out) {
  int bl = blockIdx.x * 256 + threadIdx.x;
  int b = bl >> 11, l = bl & (LL - 1);
  float a0 = 0.0f, a1 = 0.0f;
  const float* up = U + (size_t)b * HH * LL + l;
  #pragma unroll 4
  for (int h = 0; h < HH; ++h) {
    float v = up[(size_t)h * LL];
    a0 = fmaf(v, Wo[h * 2 + 0], a0);
    a1 = fmaf(v, Wo[h * 2 + 1], a1);
  }
  out[(size_t)bl * 2 + 0] = a0 + bo[0];
  out[(size_t)bl * 2 + 1] = a1 + bo[1];
}

extern "C" void kernel_launch(void* const* d_in, const int* in_sizes, int n_in,
                              void* d_out, int out_size, void* d_ws, size_t ws_size,
                              hipStream_t stream) {
  const float* X      = (const float*)d_in[0];
  const float* Win    = (const float*)d_in[1];
  const float* bin    = (const float*)d_in[2];
  const float* log_dt = (const float*)d_in[3];
  const float* Cri    = (const float*)d_in[4];
  const float* lAr    = (const float*)d_in[5];
  const float* Aim    = (const float*)d_in[6];
  const float* Dp     = (const float*)d_in[7];
  const float* CW     = (const float*)d_in[8];
  const float* CB     = (const float*)d_in[9];
  const float* Wo     = (const float*)d_in[10];
  const float* bo     = (const float*)d_in[11];
  float* out = (float*)d_out;

  const size_t Pfloats   = (size_t)NNL * HH * NN2 * 4;        // 262144
  const size_t CWfloats  = (size_t)NNL * 2 * HH * HH / 2;     // 1048576
  const size_t Tabfloats = (size_t)NNL * HH * (TABB / 4);     // 16777216
  const size_t Wtfloats  = (size_t)HH * INP;                  // 98304 (hi+lo bf16)
  const size_t Xnf       = (size_t)BB * LL * INP;             // 12582912 elems
  const size_t HL        = (size_t)HH * LL;                   // 1048576

  float* P = (float*)d_ws;
  __hip_bfloat16* CWb = (__hip_bfloat16*)(P + Pfloats);
  char* Tab = (char*)(P + Pfloats + CWfloats);
  __hip_bfloat16* Wthi = (__hip_bfloat16*)(P + Pfloats + CWfloats + Tabfloats);
  __hip_bfloat16* Wtlo = Wthi + Wtfloats;
  __hip_bfloat16* Xhi  = (__hip_bfloat16*)(P + Pfloats + CWfloats + Tabfloats + Wtfloats);
  __hip_bfloat16* Xlo  = Xhi + Xnf;
  size_t head = Pfloats + CWfloats + Tabfloats + Wtfloats + Xnf;

  size_t ws_floats = ws_size / sizeof(float);
  size_t avail = (ws_floats > head) ? (ws_floats - head) : 0;
  int G = (int)(avail / (HL + HL / 2));   // U fp32 + Ybf/Yt bf16
  if (G >= 32) G = 32;
  else if (G >= 16) G = 16;
  else if (G >= 8) G = 8;
  else if (G >= 4) G = 4;
  else if (G >= 2) G = 2;
  else G = 1;

  float* U = P + head;
  __hip_bfloat16* Ybf = (__hip_bfloat16*)(U + (size_t)G * HL);
  __hip_bfloat16* Yt  = Ybf + (size_t)G * HL;

  k_params<<<(NNL * HH * NN2 + 255) / 256, 256, 0, stream>>>(log_dt, Cri, lAr, Aim, P);
  k_tables<<<NNL * HH, 64, 0, stream>>>(P, Tab);
  k_tobf16<<<(NNL * 2 * HH * HH) / 1024, 256, 0, stream>>>(CW, CWb, NNL * 2 * HH * HH);
  k_prepwt<<<(HH * INP + 255) / 256, 256, 0, stream>>>(Win, Wthi, Wtlo);
  k_splitx<<<(int)(Xnf / 1024), 256, 0, stream>>>(X, Xhi, Xlo, (int)Xnf);

  for (int b0 = 0; b0 < BB; b0 += G) {
    int g = (BB - b0 < G) ? (BB - b0) : G;
    k_ingemm<<<dim3(LL / 128, HH / 128, g), 256, 0, stream>>>(
        Xhi + (size_t)b0 * LL * INP, Xlo + (size_t)b0 * LL * INP, Wthi, Wtlo, bin, U);
    for (int layer = 0; layer < NNL; ++layer) {
      k_scan<<<g * (HH / 4), 256, 0, stream>>>(
          U, Ybf,
          Tab + (size_t)layer * HH * TABB,
          Dp + (size_t)layer * HH);
      k_transpose<<<dim3(LL / 128, HH / 32, g), 256, 0, stream>>>(Ybf, Yt);
      k_conv<<<dim3(LL / 128, HH / 64, g), 256, 0, stream>>>(
          Yt, CWb + (size_t)layer * 2 * HH * HH, CB + (size_t)layer * 2 * HH, U);
    }
    k_outgemm<<<g * LL / 256, 256, 0, stream>>>(
        U, Wo, bo, out + (size_t)b0 * LL * OUTC);
  }
}

// Round 9
// 1236.239 us; speedup vs baseline: 6.0768x; 1.0431x over previous
//
#include <hip/hip_runtime.h>
#include <hip/hip_bf16.h>
#include <math.h>

#define BB 32
#define LL 2048
#define INP 192
#define OUTC 2
#define HH 512
#define NN2 32
#define NNL 4
#define TABB 32768   // bytes of table per (layer,h)

using short8 = __attribute__((ext_vector_type(8))) short;
using f32x4  = __attribute__((ext_vector_type(4))) float;
using f32x2  = __attribute__((ext_vector_type(2))) float;

__device__ __forceinline__ float sigmoidf_(float x) {
  return 1.0f / (1.0f + expf(-x));
}
__device__ __forceinline__ unsigned short bf16bits(float x) {
  __hip_bfloat16 b = __float2bfloat16(x);
  return __builtin_bit_cast(unsigned short, b);
}
__device__ __forceinline__ float bfval(unsigned short b) {
  unsigned int u = (unsigned int)b << 16;
  return __builtin_bit_cast(float, u);
}
// Abramowitz-Stegun 7.1.26 erf (max err 1.5e-7) based exact-GELU
__device__ __forceinline__ float gelu_fast(float x) {
  float s = x * 0.70710678118654752f;
  float ax = fabsf(s);
  float tt = 1.0f / fmaf(0.3275911f, ax, 1.0f);
  float p = fmaf(1.061405429f, tt, -1.453152027f);
  p = fmaf(p, tt, 1.421413741f);
  p = fmaf(p, tt, -0.284496736f);
  p = fmaf(p, tt, 0.254829592f);
  float e = __expf(-s * s);
  float er = 1.0f - p * tt * e;
  er = copysignf(er, s);
  return 0.5f * x * (1.0f + er);
}
__device__ __forceinline__ void gload16(const void* gsrc, void* ldst) {
  __builtin_amdgcn_global_load_lds(
      (const __attribute__((address_space(1))) void*)gsrc,
      (__attribute__((address_space(3))) void*)ldst, 16, 0, 0);
}

// ---------------------------------------------------------------------------
// P[NL][H][N2][4] = {w_re, w_im, c2_re, c2_im}
// ---------------------------------------------------------------------------
__global__ __launch_bounds__(256) void k_params(const float* __restrict__ log_dt,
                                                const float* __restrict__ Cri,
                                                const float* __restrict__ lAr,
                                                const float* __restrict__ Aim,
                                                float* __restrict__ P) {
  int idx = blockIdx.x * 256 + threadIdx.x;
  if (idx >= NNL * HH * NN2) return;
  float dt  = expf(log_dt[idx / NN2]);
  float Are = -expf(lAr[idx]);
  float Aimv = Aim[idx];
  float dre = Are * dt, dim = Aimv * dt;
  float er = expf(dre);
  float wrv = er * cosf(dim);
  float wiv = er * sinf(dim);
  float Er = wrv - 1.0f, Ei = wiv;
  float den = Are * Are + Aimv * Aimv;
  float Fr = (Er * Are + Ei * Aimv) / den;
  float Fi = (Ei * Are - Er * Aimv) / den;
  float Cre = Cri[idx * 2 + 0], Cim = Cri[idx * 2 + 1];
  P[idx * 4 + 0] = wrv;
  P[idx * 4 + 1] = wiv;
  P[idx * 4 + 2] = 2.0f * (Cre * Fr - Cim * Fi);
  P[idx * 4 + 3] = 2.0f * (Cre * Fi + Cim * Fr);
}

// ---------------------------------------------------------------------------
// Build per-(layer,h) MFMA fragment tables (split bf16 hi/lo) + scan tables.
// (unchanged from round 7; see comments there)
// ---------------------------------------------------------------------------
__global__ __launch_bounds__(64) void k_tables(const float* __restrict__ P,
                                               char* __restrict__ Tab) {
  __shared__ float kk[32];
  int tid = threadIdx.x;
  int lh = blockIdx.x;
  char* tb = Tab + (size_t)lh * TABB;
  if (tid < 32) {
    int n = tid;
    const float4 pq = reinterpret_cast<const float4*>(P)[(size_t)lh * NN2 + n];
    float wr = pq.x, wi = pq.y, c2r = pq.z, c2i = pq.w;
    int mt = n >> 4;
    float pr = 1.0f, pi = 0.0f;   // w^d
    for (int d = 0; d < 32; ++d) {
      {  // WA at t = 31-d
        int t_ = 31 - d;
        int lane = ((t_ >> 3) << 4) + (n & 15);
        int j = t_ & 7;
        unsigned short hr = bf16bits(pr);
        unsigned short lr = bf16bits(pr - bfval(hr));
        unsigned short hi_ = bf16bits(pi);
        unsigned short li_ = bf16bits(pi - bfval(hi_));
        *(unsigned short*)(tb + (mt * 2 + 0) * 1024 + lane * 16 + j * 2) = hr;
        *(unsigned short*)(tb + (mt * 2 + 1) * 1024 + lane * 16 + j * 2) = hi_;
        *(unsigned short*)(tb + 4096 + (mt * 2 + 0) * 1024 + lane * 16 + j * 2) = lr;
        *(unsigned short*)(tb + 4096 + (mt * 2 + 1) * 1024 + lane * 16 + j * 2) = li_;
      }
      {  // WC at t = d
        int mtT = d >> 4;
        int lane = (((n & 15) >> 2) << 4) + (d & 15);
        int jre = n & 3, jim = (n & 3) + 4;
        unsigned short hr = bf16bits(pr);
        unsigned short lr = bf16bits(pr - bfval(hr));
        float nim = -pi;
        unsigned short hi_ = bf16bits(nim);
        unsigned short li_ = bf16bits(nim - bfval(hi_));
        char* bh = tb + 8192 + (mtT * 2 + mt) * 1024 + lane * 16;
        char* bl = tb + 12288 + (mtT * 2 + mt) * 1024 + lane * 16;
        *(unsigned short*)(bh + jre * 2) = hr;
        *(unsigned short*)(bh + jim * 2) = hi_;
        *(unsigned short*)(bl + jre * 2) = lr;
        *(unsigned short*)(bl + jim * 2) = li_;
      }
      float kp = c2r * pr - c2i * pi;
      #pragma unroll
      for (int k = 1; k < 32; k <<= 1) kp += __shfl_xor(kp, k, 32);
      if (n == 0) kk[d] = kp;
      float nr = pr * wr - pi * wi;
      pi = pr * wi + pi * wr;
      pr = nr;
    }
    float w32r = pr, w32i = pi;
    float c2wr = c2r * wr - c2i * wi;
    float c2wi = c2r * wi + c2i * wr;
    int s = ((n >> 4) << 2) + (n & 3);
    int gg = (n & 15) >> 2;
    float pmr = 1.0f, pmi = 0.0f;   // w32^m
    for (int m = 0; m < 16; ++m) {
      float* q = (float*)(tb + 20480 + (size_t)((s * 64) + (gg * 16 + m)) * 24);
      q[0] = w32r; q[1] = w32i; q[2] = pmr; q[3] = pmi; q[4] = c2wr; q[5] = c2wi;
      float t2 = pmr * w32r - pmi * w32i;
      pmi = pmr * w32i + pmi * w32r;
      pmr = t2;
    }
  }
  __syncthreads();
  for (int idx = tid; idx < 1024; idx += 64) {
    int mt = idx >> 9, rem = idx & 511;
    int lane = rem >> 3, j = rem & 7;
    int tt = (mt << 4) + (lane & 15);
    int jf = ((lane >> 4) << 3) + j;
    float val = (jf <= tt) ? kk[tt - jf] : 0.0f;
    unsigned short hb = bf16bits(val);
    unsigned short lb = bf16bits(val - bfval(hb));
    *(unsigned short*)(tb + 16384 + mt * 1024 + lane * 16 + j * 2) = hb;
    *(unsigned short*)(tb + 18432 + mt * 1024 + lane * 16 + j * 2) = lb;
  }
}

// ---------------------------------------------------------------------------
// fp32 -> bf16 convert (CW weights).
// ---------------------------------------------------------------------------
__global__ __launch_bounds__(256) void k_tobf16(const float* __restrict__ src,
                                                __hip_bfloat16* __restrict__ dst,
                                                int n) {
  int i = (blockIdx.x * 256 + threadIdx.x) * 4;
  if (i >= n) return;
  float4 v = *reinterpret_cast<const float4*>(&src[i]);
  dst[i + 0] = __float2bfloat16(v.x);
  dst[i + 1] = __float2bfloat16(v.y);
  dst[i + 2] = __float2bfloat16(v.z);
  dst[i + 3] = __float2bfloat16(v.w);
}

// ---------------------------------------------------------------------------
// Split X fp32 -> Xhi/Xlo bf16 planes (same [b][l][k] layout).
// ---------------------------------------------------------------------------
__global__ __launch_bounds__(256) void k_splitx(const float* __restrict__ src,
                                                __hip_bfloat16* __restrict__ hi,
                                                __hip_bfloat16* __restrict__ lo,
                                                int n) {
  int i = (blockIdx.x * 256 + threadIdx.x) * 4;
  if (i >= n) return;
  float4 v = *reinterpret_cast<const float4*>(&src[i]);
  float vv[4] = {v.x, v.y, v.z, v.w};
  unsigned short hb[4], lb[4];
  #pragma unroll
  for (int j = 0; j < 4; ++j) {
    hb[j] = bf16bits(vv[j]);
    lb[j] = bf16bits(vv[j] - bfval(hb[j]));
  }
  *reinterpret_cast<uint2*>(hi + i) = make_uint2(
      (unsigned)hb[0] | ((unsigned)hb[1] << 16), (unsigned)hb[2] | ((unsigned)hb[3] << 16));
  *reinterpret_cast<uint2*>(lo + i) = make_uint2(
      (unsigned)lb[0] | ((unsigned)lb[1] << 16), (unsigned)lb[2] | ((unsigned)lb[3] << 16));
}

// ---------------------------------------------------------------------------
// W[k][h] fp32 -> Wt hi/lo bf16 [h][k] (transposed, split). One-time, tiny.
// ---------------------------------------------------------------------------
__global__ __launch_bounds__(256) void k_prepwt(const float* __restrict__ W,
                                                __hip_bfloat16* __restrict__ hi,
                                                __hip_bfloat16* __restrict__ lo) {
  int idx = blockIdx.x * 256 + threadIdx.x;   // h*INP + k
  if (idx >= HH * INP) return;
  int h = idx / INP, k = idx - h * INP;
  float v = W[(size_t)k * HH + h];
  unsigned short hb = bf16bits(v);
  hi[idx] = __builtin_bit_cast(__hip_bfloat16, hb);
  lo[idx] = __float2bfloat16(v - bfval(hb));
}

// ---------------------------------------------------------------------------
// Input GEMM, bf16 MFMA split (unchanged from round 8).
// ---------------------------------------------------------------------------
__global__ __launch_bounds__(256) void k_ingemm(const __hip_bfloat16* __restrict__ Xhi,
                                                const __hip_bfloat16* __restrict__ Xlo,
                                                const __hip_bfloat16* __restrict__ Wthi,
                                                const __hip_bfloat16* __restrict__ Wtlo,
                                                const float* __restrict__ bias,
                                                float* __restrict__ U) {
  int lt = blockIdx.x * 128;
  int ht = blockIdx.y * 128;
  int b  = blockIdx.z;
  int t = threadIdx.x;
  int wid = t >> 6, lane = t & 63;
  int wrow = wid >> 1, wcol = wid & 1;
  int l15 = lane & 15, g = lane >> 4;

  const short* Xh = (const short*)Xhi + (size_t)b * LL * INP;
  const short* Xl = (const short*)Xlo + (size_t)b * LL * INP;
  const short* Bh = (const short*)Wthi;
  const short* Bl = (const short*)Wtlo;

  f32x4 acc[4][4];
  #pragma unroll
  for (int m = 0; m < 4; ++m)
    #pragma unroll
    for (int n = 0; n < 4; ++n) acc[m][n] = f32x4{0.f, 0.f, 0.f, 0.f};

  int lbase = lt + wrow * 64 + l15;
  int hbase = ht + wcol * 64 + l15;

  #pragma unroll
  for (int ks = 0; ks < 6; ++ks) {
    int k0 = ks * 32 + 8 * g;
    short8 ah[4], al[4], bh[4], bl[4];
    #pragma unroll
    for (int m = 0; m < 4; ++m) {
      size_t off = (size_t)(lbase + m * 16) * INP + k0;
      ah[m] = *reinterpret_cast<const short8*>(Xh + off);
      al[m] = *reinterpret_cast<const short8*>(Xl + off);
    }
    #pragma unroll
    for (int n = 0; n < 4; ++n) {
      size_t off = (size_t)(hbase + n * 16) * INP + k0;
      bh[n] = *reinterpret_cast<const short8*>(Bh + off);
      bl[n] = *reinterpret_cast<const short8*>(Bl + off);
    }
    #pragma unroll
    for (int m = 0; m < 4; ++m)
      #pragma unroll
      for (int n = 0; n < 4; ++n) {
        acc[m][n] = __builtin_amdgcn_mfma_f32_16x16x32_bf16(ah[m], bh[n], acc[m][n], 0, 0, 0);
        acc[m][n] = __builtin_amdgcn_mfma_f32_16x16x32_bf16(ah[m], bl[n], acc[m][n], 0, 0, 0);
        acc[m][n] = __builtin_amdgcn_mfma_f32_16x16x32_bf16(al[m], bh[n], acc[m][n], 0, 0, 0);
      }
  }

  #pragma unroll
  for (int n = 0; n < 4; ++n) {
    int h = hbase + n * 16;
    float bv = bias[h];
    #pragma unroll
    for (int m = 0; m < 4; ++m) {
      int l0 = lt + wrow * 64 + m * 16 + g * 4;
      float4 o;
      o.x = acc[m][n][0] + bv;
      o.y = acc[m][n][1] + bv;
      o.z = acc[m][n][2] + bv;
      o.w = acc[m][n][3] + bv;
      *reinterpret_cast<float4*>(&U[((size_t)b * HH + h) * LL + l0]) = o;
    }
  }
}

// ---------------------------------------------------------------------------
// MFMA chunk-parallel S4D scan. NOW 512 threads = 8 rows (one h-octet of one
// b). Output written in h-octet-blocked layout Ybt[b][h>>3][l][h&7] bf16 via
// a 32 KB LDS transpose (XOR-swizzled) -> fully packed 16B stores.
// Math identical to round 7/8.
// ---------------------------------------------------------------------------
__global__ __launch_bounds__(512) void k_scan(const float* __restrict__ U,
                                              short* __restrict__ Ybt,
                                              const char* __restrict__ Tab,
                                              const float* __restrict__ Dp) {
  __shared__ short ylds[8 * 2048];   // [l][h'] with XOR swizzle, 32 KB
  int t = threadIdx.x;
  int lane = t & 63;
  int wid = t >> 6;                                   // 0..7 = h'
  int row = __builtin_amdgcn_readfirstlane(blockIdx.x * 8 + wid);
  int h = row & (HH - 1);
  const char* tb = Tab + (size_t)h * TABB;
  const float* urow = U + (size_t)row * LL;
  int g = lane >> 4, m = lane & 15;

  short8 uh[4], ul[4];
  #pragma unroll
  for (int c0 = 0; c0 < 4; ++c0) {
    const float* p = urow + 512 * c0 + 32 * m + 8 * g;
    float4 va = *reinterpret_cast<const float4*>(p);
    float4 vb = *reinterpret_cast<const float4*>(p + 4);
    float v[8] = {va.x, va.y, va.z, va.w, vb.x, vb.y, vb.z, vb.w};
    short8 hi, lo;
    #pragma unroll
    for (int j = 0; j < 8; ++j) {
      unsigned short hb = bf16bits(v[j]);
      hi[j] = (short)hb;
      lo[j] = (short)bf16bits(v[j] - bfval(hb));
    }
    uh[c0] = hi;
    ul[c0] = lo;
  }

  f32x4 Z[2][2][4];
  #pragma unroll
  for (int mt = 0; mt < 2; ++mt)
    #pragma unroll
    for (int reim = 0; reim < 2; ++reim) {
      short8 whi = *reinterpret_cast<const short8*>(tb + (mt * 2 + reim) * 1024 + lane * 16);
      short8 wlo = *reinterpret_cast<const short8*>(tb + 4096 + (mt * 2 + reim) * 1024 + lane * 16);
      #pragma unroll
      for (int c0 = 0; c0 < 4; ++c0) {
        f32x4 z = {0.f, 0.f, 0.f, 0.f};
        z = __builtin_amdgcn_mfma_f32_16x16x32_bf16(whi, uh[c0], z, 0, 0, 0);
        z = __builtin_amdgcn_mfma_f32_16x16x32_bf16(whi, ul[c0], z, 0, 0, 0);
        z = __builtin_amdgcn_mfma_f32_16x16x32_bf16(wlo, uh[c0], z, 0, 0, 0);
        Z[mt][reim][c0] = z;
      }
    }

  float aR[8][4], aI[8][4];
  #pragma unroll
  for (int s = 0; s < 8; ++s) {
    int mt = s >> 2, i = s & 3;
    const char* plb = tb + 20480 + (size_t)(s * 64 + lane) * 24;
    f32x2 w32 = *reinterpret_cast<const f32x2*>(plb);
    f32x2 w32m = *reinterpret_cast<const f32x2*>(plb + 8);
    f32x2 c2w = *reinterpret_cast<const f32x2*>(plb + 16);
    float r1r = w32[0], r1i = w32[1];
    float r2r = r1r * r1r - r1i * r1i, r2i = 2.f * r1r * r1i;
    float r4r = r2r * r2r - r2i * r2i, r4i = 2.f * r2r * r2i;
    float r8r = r4r * r4r - r4i * r4i, r8i = 2.f * r4r * r4i;
    float w16r = r8r * r8r - r8i * r8i, w16i = 2.f * r8r * r8i;
    float Sr = 0.f, Si = 0.f;
    #pragma unroll
    for (int c0 = 0; c0 < 4; ++c0) {
      float Pr = Z[mt][0][c0][i], Pi = Z[mt][1][c0][i];
      {
        float qr = __shfl_up(Pr, 1u, 16), qi = __shfl_up(Pi, 1u, 16);
        if (m < 1) { qr = 0.f; qi = 0.f; }
        Pr = fmaf(r1r, qr, fmaf(-r1i, qi, Pr));
        Pi = fmaf(r1r, qi, fmaf(r1i, qr, Pi));
      }
      {
        float qr = __shfl_up(Pr, 2u, 16), qi = __shfl_up(Pi, 2u, 16);
        if (m < 2) { qr = 0.f; qi = 0.f; }
        Pr = fmaf(r2r, qr, fmaf(-r2i, qi, Pr));
        Pi = fmaf(r2r, qi, fmaf(r2i, qr, Pi));
      }
      {
        float qr = __shfl_up(Pr, 4u, 16), qi = __shfl_up(Pi, 4u, 16);
        if (m < 4) { qr = 0.f; qi = 0.f; }
        Pr = fmaf(r4r, qr, fmaf(-r4i, qi, Pr));
        Pi = fmaf(r4r, qi, fmaf(r4i, qr, Pi));
      }
      {
        float qr = __shfl_up(Pr, 8u, 16), qi = __shfl_up(Pi, 8u, 16);
        if (m < 8) { qr = 0.f; qi = 0.f; }
        Pr = fmaf(r8r, qr, fmaf(-r8i, qi, Pr));
        Pi = fmaf(r8r, qi, fmaf(r8i, qr, Pi));
      }
      float eqr = __shfl_up(Pr, 1u, 16), eqi = __shfl_up(Pi, 1u, 16);
      if (m == 0) { eqr = 0.f; eqi = 0.f; }
      float Er = fmaf(w32m[0], Sr, fmaf(-w32m[1], Si, eqr));
      float Ei = fmaf(w32m[0], Si, fmaf(w32m[1], Sr, eqi));
      aR[s][c0] = c2w[0] * Er - c2w[1] * Ei;
      aI[s][c0] = c2w[0] * Ei + c2w[1] * Er;
      float lr = __shfl(Pr, 15, 16), li = __shfl(Pi, 15, 16);
      float nS = fmaf(w16r, Sr, fmaf(-w16i, Si, lr));
      Si = fmaf(w16r, Si, fmaf(w16i, Sr, li));
      Sr = nS;
    }
  }

  short8 afh[2][4], afl[2][4];
  #pragma unroll
  for (int kt = 0; kt < 2; ++kt)
    #pragma unroll
    for (int c0 = 0; c0 < 4; ++c0) {
      float av[8] = {aR[kt * 4 + 0][c0], aR[kt * 4 + 1][c0], aR[kt * 4 + 2][c0], aR[kt * 4 + 3][c0],
                     aI[kt * 4 + 0][c0], aI[kt * 4 + 1][c0], aI[kt * 4 + 2][c0], aI[kt * 4 + 3][c0]};
      short8 hi, lo;
      #pragma unroll
      for (int j = 0; j < 8; ++j) {
        unsigned short hb = bf16bits(av[j]);
        hi[j] = (short)hb;
        lo[j] = (short)bf16bits(av[j] - bfval(hb));
      }
      afh[kt][c0] = hi;
      afl[kt][c0] = lo;
    }

  f32x4 y[2][4];
  #pragma unroll
  for (int mtT = 0; mtT < 2; ++mtT) {
    short8 fh = *reinterpret_cast<const short8*>(tb + 16384 + mtT * 1024 + lane * 16);
    short8 fl = *reinterpret_cast<const short8*>(tb + 18432 + mtT * 1024 + lane * 16);
    short8 wch0 = *reinterpret_cast<const short8*>(tb + 8192 + (mtT * 2 + 0) * 1024 + lane * 16);
    short8 wcl0 = *reinterpret_cast<const short8*>(tb + 12288 + (mtT * 2 + 0) * 1024 + lane * 16);
    short8 wch1 = *reinterpret_cast<const short8*>(tb + 8192 + (mtT * 2 + 1) * 1024 + lane * 16);
    short8 wcl1 = *reinterpret_cast<const short8*>(tb + 12288 + (mtT * 2 + 1) * 1024 + lane * 16);
    #pragma unroll
    for (int c0 = 0; c0 < 4; ++c0) {
      f32x4 acc = {0.f, 0.f, 0.f, 0.f};
      acc = __builtin_amdgcn_mfma_f32_16x16x32_bf16(fh, uh[c0], acc, 0, 0, 0);
      acc = __builtin_amdgcn_mfma_f32_16x16x32_bf16(fh, ul[c0], acc, 0, 0, 0);
      acc = __builtin_amdgcn_mfma_f32_16x16x32_bf16(fl, uh[c0], acc, 0, 0, 0);
      acc = __builtin_amdgcn_mfma_f32_16x16x32_bf16(wch0, afh[0][c0], acc, 0, 0, 0);
      acc = __builtin_amdgcn_mfma_f32_16x16x32_bf16(wch0, afl[0][c0], acc, 0, 0, 0);
      acc = __builtin_amdgcn_mfma_f32_16x16x32_bf16(wcl0, afh[0][c0], acc, 0, 0, 0);
      acc = __builtin_amdgcn_mfma_f32_16x16x32_bf16(wch1, afh[1][c0], acc, 0, 0, 0);
      acc = __builtin_amdgcn_mfma_f32_16x16x32_bf16(wch1, afl[1][c0], acc, 0, 0, 0);
      acc = __builtin_amdgcn_mfma_f32_16x16x32_bf16(wcl1, afh[1][c0], acc, 0, 0, 0);
      y[mtT][c0] = acc;
    }
  }

  // epilogue: + D*u, GELU, write bf16 into LDS [l][h'] (XOR-swizzled)
  float Dv = Dp[h];
  #pragma unroll
  for (int mtT = 0; mtT < 2; ++mtT)
    #pragma unroll
    for (int c0 = 0; c0 < 4; ++c0) {
      int eb = 512 * c0 + 32 * m + 16 * mtT + 4 * g;
      float4 uu = *reinterpret_cast<const float4*>(urow + eb);
      f32x4 vv = y[mtT][c0];
      unsigned short bv[4];
      bv[0] = bf16bits(gelu_fast(fmaf(Dv, uu.x, vv[0])));
      bv[1] = bf16bits(gelu_fast(fmaf(Dv, uu.y, vv[1])));
      bv[2] = bf16bits(gelu_fast(fmaf(Dv, uu.z, vv[2])));
      bv[3] = bf16bits(gelu_fast(fmaf(Dv, uu.w, vv[3])));
      int ymask = ((eb >> 5) & 7) << 4;
      #pragma unroll
      for (int k = 0; k < 4; ++k) {
        *(short*)((char*)ylds + (((eb + k) * 16 + wid * 2) ^ ymask)) = (short)bv[k];
      }
    }
  __syncthreads();
  // packed 16B stores: Ybt[(blockIdx.x * 2048 + l) * 8 + 0..7]
  #pragma unroll
  for (int i = 0; i < 4; ++i) {
    int l = t + 512 * i;
    int ymask = ((l >> 5) & 7) << 4;
    uint4 v = *reinterpret_cast<const uint4*>((const char*)ylds + ((l * 16) ^ ymask));
    *reinterpret_cast<uint4*>(Ybt + ((size_t)blockIdx.x * 2048 + l) * 8) = v;
  }
}

// ---------------------------------------------------------------------------
// conv1x1 + GLU, bf16 MFMA 16x16x32. B operand loaded DIRECTLY from the
// h-octet-blocked Ybt layout (no B LDS, no transpose kernel). A (CW) staged
// in LDS via gload16 with XOR swizzle (16 KB).
// ---------------------------------------------------------------------------
__global__ __launch_bounds__(256) void k_conv(const short* __restrict__ Ybt,
                                              const __hip_bfloat16* __restrict__ CWb,
                                              const float* __restrict__ CB,
                                              float* __restrict__ U) {
  __shared__ short Alds[128 * 64];
  int lt = blockIdx.x * 128;
  int ot = blockIdx.y * 64;
  int b  = blockIdx.z;
  int t = threadIdx.x;
  int wid = t >> 6, lane = t & 63;
  int wr = wid >> 1, wc = wid & 1;
  int l15 = lane & 15, l4 = lane >> 4;
  f32x4 zero = {0.f, 0.f, 0.f, 0.f};
  f32x4 accA[2][4], accG[2][4];
  #pragma unroll
  for (int m = 0; m < 2; ++m)
    #pragma unroll
    for (int n = 0; n < 4; ++n) { accA[m][n] = zero; accG[m][n] = zero; }

  const short* Yb = Ybt + (size_t)b * 64 * 2048 * 8;
  const char* Wb = (const char*)CWb;

  for (int kt = 0; kt < HH; kt += 64) {
    // stage A (CW rows): 16KB, 4 x 16B per thread
    #pragma unroll
    for (int it = 0; it < 4; ++it) {
      int d = 16 * (t + 256 * it);
      int rowl = d >> 7, cb = d & 127;
      int orow = (rowl < 64) ? (ot + rowl) : (448 + ot + rowl);
      gload16(Wb + (size_t)orow * 1024 + kt * 2 + (cb ^ ((rowl & 7) << 4)),
              (char*)Alds + d);
    }
    // B fragments: direct coalesced 16B loads from Ybt (no LDS)
    short8 bfrag[2][4];
    #pragma unroll
    for (int ks = 0; ks < 2; ++ks)
      #pragma unroll
      for (int n = 0; n < 4; ++n) {
        int l = lt + wc * 64 + n * 16 + l15;
        int octg = (kt >> 3) + ks * 4 + l4;
        bfrag[ks][n] = *reinterpret_cast<const short8*>(
            Yb + ((size_t)octg * 2048 + l) * 8);
      }
    __syncthreads();
    #pragma unroll
    for (int ks = 0; ks < 2; ++ks) {
      short8 af[4];
      #pragma unroll
      for (int m = 0; m < 4; ++m) {
        int mrow = ((m < 2) ? (wr * 32 + m * 16) : (64 + wr * 32 + (m - 2) * 16)) + l15;
        int colb = (ks * 64 + 16 * l4) ^ ((mrow & 7) << 4);
        af[m] = *reinterpret_cast<const short8*>((const char*)Alds + mrow * 128 + colb);
      }
      #pragma unroll
      for (int m = 0; m < 2; ++m)
        #pragma unroll
        for (int n = 0; n < 4; ++n) {
          accA[m][n] = __builtin_amdgcn_mfma_f32_16x16x32_bf16(af[m], bfrag[ks][n], accA[m][n], 0, 0, 0);
          accG[m][n] = __builtin_amdgcn_mfma_f32_16x16x32_bf16(af[m + 2], bfrag[ks][n], accG[m][n], 0, 0, 0);
        }
    }
    __syncthreads();
  }
  #pragma unroll
  for (int m = 0; m < 2; ++m) {
    #pragma unroll
    for (int r = 0; r < 4; ++r) {
      int rowl = wr * 32 + m * 16 + l4 * 4 + r;
      float ba = CB[ot + rowl];
      float bg = CB[512 + ot + rowl];
      float* urow_ = U + ((size_t)b * HH + ot + rowl) * LL + lt + wc * 64;
      #pragma unroll
      for (int n = 0; n < 4; ++n) {
        float a = accA[m][n][r] + ba;
        float g = accG[m][n][r] + bg;
        urow_[n * 16 + l15] = a * sigmoidf_(g);
      }
    }
  }
}

// ---------------------------------------------------------------------------
// Output projection (fp32 out).
// ---------------------------------------------------------------------------
__global__ __launch_bounds__(256) void k_outgemm(const float* __restrict__ U,
                                                 const float* __restrict__ Wo,
                                                 const float* __restrict__ bo,
                                                 float* __restrict__ out) {
  int bl = blockIdx.x * 256 + threadIdx.x;
  int b = bl >> 11, l = bl & (LL - 1);
  float a0 = 0.0f, a1 = 0.0f;
  const float* up = U + (size_t)b * HH * LL + l;
  #pragma unroll 4
  for (int h = 0; h < HH; ++h) {
    float v = up[(size_t)h * LL];
    a0 = fmaf(v, Wo[h * 2 + 0], a0);
    a1 = fmaf(v, Wo[h * 2 + 1], a1);
  }
  out[(size_t)bl * 2 + 0] = a0 + bo[0];
  out[(size_t)bl * 2 + 1] = a1 + bo[1];
}

extern "C" void kernel_launch(void* const* d_in, const int* in_sizes, int n_in,
                              void* d_out, int out_size, void* d_ws, size_t ws_size,
                              hipStream_t stream) {
  const float* X      = (const float*)d_in[0];
  const float* Win    = (const float*)d_in[1];
  const float* bin    = (const float*)d_in[2];
  const float* log_dt = (const float*)d_in[3];
  const float* Cri    = (const float*)d_in[4];
  const float* lAr    = (const float*)d_in[5];
  const float* Aim    = (const float*)d_in[6];
  const float* Dp     = (const float*)d_in[7];
  const float* CW     = (const float*)d_in[8];
  const float* CB     = (const float*)d_in[9];
  const float* Wo     = (const float*)d_in[10];
  const float* bo     = (const float*)d_in[11];
  float* out = (float*)d_out;

  const size_t Pfloats   = (size_t)NNL * HH * NN2 * 4;        // 262144
  const size_t CWfloats  = (size_t)NNL * 2 * HH * HH / 2;     // 1048576
  const size_t Tabfloats = (size_t)NNL * HH * (TABB / 4);     // 16777216
  const size_t Wtfloats  = (size_t)HH * INP;                  // 98304 (hi+lo bf16)
  const size_t Xnf       = (size_t)BB * LL * INP;             // 12582912 elems
  const size_t HL        = (size_t)HH * LL;                   // 1048576

  float* P = (float*)d_ws;
  __hip_bfloat16* CWb = (__hip_bfloat16*)(P + Pfloats);
  char* Tab = (char*)(P + Pfloats + CWfloats);
  __hip_bfloat16* Wthi = (__hip_bfloat16*)(P + Pfloats + CWfloats + Tabfloats);
  __hip_bfloat16* Wtlo = Wthi + Wtfloats;
  __hip_bfloat16* Xhi  = (__hip_bfloat16*)(P + Pfloats + CWfloats + Tabfloats + Wtfloats);
  __hip_bfloat16* Xlo  = Xhi + Xnf;
  size_t head = Pfloats + CWfloats + Tabfloats + Wtfloats + Xnf;

  size_t ws_floats = ws_size / sizeof(float);
  size_t avail = (ws_floats > head) ? (ws_floats - head) : 0;
  int G = (int)(avail / (HL + HL / 2));   // U fp32 + Ybt bf16
  if (G >= 32) G = 32;
  else if (G >= 16) G = 16;
  else if (G >= 8) G = 8;
  else if (G >= 4) G = 4;
  else if (G >= 2) G = 2;
  else G = 1;

  float* U = P + head;
  short* Ybt = (short*)(U + (size_t)G * HL);

  k_params<<<(NNL * HH * NN2 + 255) / 256, 256, 0, stream>>>(log_dt, Cri, lAr, Aim, P);
  k_tables<<<NNL * HH, 64, 0, stream>>>(P, Tab);
  k_tobf16<<<(NNL * 2 * HH * HH) / 1024, 256, 0, stream>>>(CW, CWb, NNL * 2 * HH * HH);
  k_prepwt<<<(HH * INP + 255) / 256, 256, 0, stream>>>(Win, Wthi, Wtlo);
  k_splitx<<<(int)(Xnf / 1024), 256, 0, stream>>>(X, Xhi, Xlo, (int)Xnf);

  for (int b0 = 0; b0 < BB; b0 += G) {
    int g = (BB - b0 < G) ? (BB - b0) : G;
    k_ingemm<<<dim3(LL / 128, HH / 128, g), 256, 0, stream>>>(
        Xhi + (size_t)b0 * LL * INP, Xlo + (size_t)b0 * LL * INP, Wthi, Wtlo, bin, U);
    for (int layer = 0; layer < NNL; ++layer) {
      k_scan<<<g * (HH / 8), 512, 0, stream>>>(
          U, Ybt,
          Tab + (size_t)layer * HH * TABB,
          Dp + (size_t)layer * HH);
      k_conv<<<dim3(LL / 128, HH / 64, g), 256, 0, stream>>>(
          Ybt, CWb + (size_t)layer * 2 * HH * HH, CB + (size_t)layer * 2 * HH, U);
    }
    k_outgemm<<<g * LL / 256, 256, 0, stream>>>(
        U, Wo, bo, out + (size_t)b0 * LL * OUTC);
  }
}